// Round 15
// baseline (1855.694 us; speedup 1.0000x reference)
//
#include <hip/hip_runtime.h>
#include <hip/hip_bf16.h>
#include <math.h>

#define BN_RS 0.99999500003749977f  // 1/sqrt(1 + 1e-5)

typedef __attribute__((ext_vector_type(8))) __bf16 bf16x8;
typedef __attribute__((ext_vector_type(4))) float f32x4;

union U16 { uint4 u; bf16x8 v; __hip_bfloat16 h[8]; };
union U8  { uint2 u; __hip_bfloat16 h[4]; };

__device__ __forceinline__ float sigf(float v) { return 1.0f / (1.0f + expf(-v)); }

// ================= weight repack =================
__global__ __launch_bounds__(256)
void repack_conv_w_k(const float* __restrict__ w, __hip_bfloat16* __restrict__ wb,
                     int taps, int Co, int Ci, int CoT, int Kp)
{
    int i = blockIdx.x * 256 + threadIdx.x;
    int tot = taps * CoT * Kp;
    if (i >= tot) return;
    int k = i % Kp, n = (i / Kp) % CoT, t = i / (Kp * CoT);
    float v = (n < Co && k < Ci) ? w[((long)n * Ci + k) * taps + t] : 0.0f;
    wb[i] = __float2bfloat16(v);
}
__global__ __launch_bounds__(256)
void repack_conv_w_ilv_k(const float* __restrict__ w, __hip_bfloat16* __restrict__ wb,
                         int taps, int Co, int Ci, int CoT, int Kp)
{
    int i = blockIdx.x * 256 + threadIdx.x;
    int tot = taps * CoT * Kp;
    if (i >= tot) return;
    int k = i % Kp, n = (i / Kp) % CoT, t = i / (Kp * CoT);
    int grp = n >> 6, r = n & 63;
    int c = (grp << 6) + (r & 15) * 4 + (r >> 4);
    float v = (c < Co && k < Ci) ? w[((long)c * Ci + k) * taps + t] : 0.0f;
    wb[i] = __float2bfloat16(v);
}
__global__ __launch_bounds__(256)
void repack_deconv_w_ilv_k(const float* __restrict__ w, __hip_bfloat16* __restrict__ wb,
                           int Co, int Ci)
{
    int i = blockIdx.x * 256 + threadIdx.x;
    int tot = 4 * Co * Ci;
    if (i >= tot) return;
    int k = i % Ci, n = (i / Ci) % Co, q = i / (Ci * Co);
    int grp = n >> 6, r = n & 63;
    int c = (grp << 6) + (r & 15) * 4 + (r >> 4);
    wb[i] = __float2bfloat16(w[((long)k * Co + c) * 4 + q]);
}

// ================= zero the 1-px halo of a padded NHWC buffer =================
__global__ __launch_bounds__(256)
void zero_halo_k(__hip_bfloat16* __restrict__ buf, int H, int W, int C, int B)
{
    const int P = W + 2;
    const long per = (long)(2 * P + 2 * H) * C;
    long idx = (long)blockIdx.x * 256 + threadIdx.x;
    if (idx >= per * B) return;
    int b = (int)(idx / per);
    long r = idx % per;
    long off;
    if (r < (long)2 * P * C) {
        int row = (r >= (long)P * C) ? (H + 1) : 0;
        long r2 = r % ((long)P * C);
        off = (((long)b * (H + 2) + row) * P) * C + r2;
    } else {
        long r2 = r - (long)2 * P * C;
        int row = 1 + (int)(r2 / (2 * C));
        int side = (int)((r2 / C) & 1);
        int ch = (int)(r2 % C);
        off = (((long)b * (H + 2) + row) * P + (side ? (W + 1) : 0)) * C + ch;
    }
    buf[off] = __float2bfloat16(0.0f);
}

// ================= conv1 (3->32, scalar fp32, writes bf16 NHWC padded-interior) =================
__global__ __launch_bounds__(256)
void conv1_k(const float* __restrict__ x, const float* __restrict__ w,
             const float* __restrict__ cb, const float* __restrict__ g,
             const float* __restrict__ bb, __hip_bfloat16* __restrict__ out)
{
    __shared__ float sw[216];
    const int tid = threadIdx.x;
    const int b = blockIdx.z >> 2, cg = blockIdx.z & 3, co0 = cg * 8;
    for (int i = tid; i < 216; i += 256) {
        int t = i % 9, co = (i / 9) % 8, ci = i / 72;
        sw[i] = w[((co0 + co) * 3 + ci) * 9 + t];
    }
    __syncthreads();
    const int tx = tid & 15, ty = tid >> 4;
    const int y = blockIdx.y * 16 + ty;
    const int xs = blockIdx.x * 64 + tx;
    float acc[4][8];
#pragma unroll
    for (int p = 0; p < 4; ++p)
#pragma unroll
        for (int c = 0; c < 8; ++c) acc[p][c] = 0.0f;
    for (int ci = 0; ci < 3; ++ci) {
        const float* plane = x + ((long)b * 3 + ci) * 65536;
#pragma unroll
        for (int t = 0; t < 9; ++t) {
            const int dy = t / 3 - 1, dx = t % 3 - 1;
            const int yy = y + dy;
            if ((unsigned)yy < 256u) {
                const float* row = plane + yy * 256;
                float wsr[8];
#pragma unroll
                for (int c = 0; c < 8; ++c) wsr[c] = sw[ci * 72 + c * 9 + t];
#pragma unroll
                for (int p = 0; p < 4; ++p) {
                    const int xx = xs + p * 16 + dx;
                    const float v = ((unsigned)xx < 256u) ? row[xx] : 0.0f;
#pragma unroll
                    for (int c = 0; c < 8; ++c) acc[p][c] = fmaf(v, wsr[c], acc[p][c]);
                }
            }
        }
    }
#pragma unroll
    for (int p = 0; p < 4; ++p) {
        U16 o;
#pragma unroll
        for (int c = 0; c < 8; ++c) {
            const int cc = co0 + c;
            float v = fmaxf(acc[p][c] + cb[cc], 0.0f) * (g[cc] * BN_RS) + bb[cc];
            o.h[c] = __float2bfloat16(v);
        }
        *(uint4*)(void*)(out + ((long)b * 2130048L + ((long)y * 258 + xs + p * 16) * 32) + co0) = o.u;
    }
}

// ================= MFMA conv 3x3 (implicit GEMM, halo-padded input) =================
template<int MI>
__global__ __launch_bounds__(256)
void mfma_conv_k(const __hip_bfloat16* __restrict__ in,
                 const __hip_bfloat16* __restrict__ wb,
                 const float* __restrict__ cbias,
                 const float* __restrict__ bng, const float* __restrict__ bnb,
                 __hip_bfloat16* __restrict__ out_bf,
                 int H, int W, int Cin, int PIT, long bstride, long obstride, int OPIT,
                 int CoutT, int CG, int S)
{
    const int tid = threadIdx.x;
    const int wid = tid >> 6, lane = tid & 63;
    const int ln = lane & 15, kg = lane >> 4;
    const int nx = gridDim.x;
    const int bx = (blockIdx.x & 7) * (nx >> 3) + (blockIdx.x >> 3);
    const int u = bx * 4 + wid;
    const int y = u / S, x0 = (u % S) * (MI * 16);
    const int b = blockIdx.z / CG, cg = blockIdx.z % CG;
    const int co0 = cg * 64;
    const int KC = Cin >> 5;

    f32x4 acc[MI][4];
#pragma unroll
    for (int i = 0; i < MI; ++i)
#pragma unroll
        for (int j = 0; j < 4; ++j) acc[i][j] = f32x4{0.f, 0.f, 0.f, 0.f};

    for (int kc = 0; kc < KC; ++kc) {
        const int kofs = kc * 32 + kg * 8;
#pragma unroll
        for (int t = 0; t < 9; ++t) {
            const int dy = t / 3 - 1, dx = t % 3 - 1;
            bf16x8 wfr[4];
#pragma unroll
            for (int ni = 0; ni < 4; ++ni)
                wfr[ni] = *(const bf16x8*)(const void*)(wb + ((long)t * CoutT + co0 + ni * 16 + ln) * Cin + kofs);
            U16 av[MI];
            const long rowb = (long)b * bstride + (long)(y + dy) * PIT * Cin + kofs;
#pragma unroll
            for (int mi = 0; mi < MI; ++mi)
                av[mi].u = *(const uint4*)(const void*)(in + rowb + (long)(x0 + mi * 16 + ln + dx) * Cin);
#pragma unroll
            for (int mi = 0; mi < MI; ++mi)
#pragma unroll
                for (int ni = 0; ni < 4; ++ni)
                    acc[mi][ni] = __builtin_amdgcn_mfma_f32_16x16x32_bf16(av[mi].v, wfr[ni], acc[mi][ni], 0, 0, 0);
        }
    }
#pragma unroll
    for (int mi = 0; mi < MI; ++mi) {
#pragma unroll
        for (int r = 0; r < 4; ++r) {
            const int px = x0 + mi * 16 + kg * 4 + r;
            const long pb = (long)b * obstride + ((long)y * OPIT + px) * CoutT + co0;
            U8 o;
#pragma unroll
            for (int ni = 0; ni < 4; ++ni) {
                const int c = co0 + ln * 4 + ni;
                float v = acc[mi][ni][r] + cbias[c];
                v = fmaxf(v, 0.0f) * (bng[c] * BN_RS) + bnb[c];
                o.h[ni] = __float2bfloat16(v);
            }
            *(uint2*)(void*)(out_bf + pb + ln * 4) = o.u;
        }
    }
}

// ================= MFMA deconv 2x2 + ReLU (interleaved weights, packed stores) =========
__global__ __launch_bounds__(256)
void mfma_deconv_k(const __hip_bfloat16* __restrict__ in,
                   const __hip_bfloat16* __restrict__ wb,
                   const float* __restrict__ bias,
                   __hip_bfloat16* __restrict__ out,
                   int H, int W, int Cin, int CoutT, int CG, int S)
{
    const int tid = threadIdx.x;
    const int wid = tid >> 6, lane = tid & 63;
    const int ln = lane & 15, kg = lane >> 4;
    const int nx = gridDim.x;
    const int bx = (blockIdx.x & 7) * (nx >> 3) + (blockIdx.x >> 3);
    const int u = bx * 4 + wid;
    const int y = u / S, x0 = (u % S) * 32;
    const int b = blockIdx.z / CG, cg = blockIdx.z % CG;
    const int co0 = cg * 64;
    const int KC = Cin >> 5;
    const long inb = (long)b * H * W * Cin;
    const int W2 = W * 2;
    const long ob = (long)b * 4 * H * W * CoutT;

    for (int q = 0; q < 4; ++q) {
        const int dy = q >> 1, dx = q & 1;
        f32x4 acc[2][4];
#pragma unroll
        for (int i = 0; i < 2; ++i)
#pragma unroll
            for (int j = 0; j < 4; ++j) acc[i][j] = f32x4{0.f, 0.f, 0.f, 0.f};
        for (int kc = 0; kc < KC; ++kc) {
            const int kofs = kc * 32 + kg * 8;
            bf16x8 wfr[4];
            U16 av[2];
#pragma unroll
            for (int ni = 0; ni < 4; ++ni)
                wfr[ni] = *(const bf16x8*)(const void*)(wb + ((long)q * CoutT + co0 + ni * 16 + ln) * Cin + kofs);
#pragma unroll
            for (int mi = 0; mi < 2; ++mi)
                av[mi].u = *(const uint4*)(const void*)(in + inb + ((long)y * W + x0 + mi * 16 + ln) * Cin + kofs);
#pragma unroll
            for (int mi = 0; mi < 2; ++mi)
#pragma unroll
                for (int ni = 0; ni < 4; ++ni)
                    acc[mi][ni] = __builtin_amdgcn_mfma_f32_16x16x32_bf16(av[mi].v, wfr[ni], acc[mi][ni], 0, 0, 0);
        }
#pragma unroll
        for (int mi = 0; mi < 2; ++mi) {
#pragma unroll
            for (int r = 0; r < 4; ++r) {
                const int xl = x0 + mi * 16 + kg * 4 + r;
                const long pb = ob + ((long)(2 * y + dy) * W2 + 2 * xl + dx) * CoutT + co0;
                U8 o;
#pragma unroll
                for (int ni = 0; ni < 4; ++ni) {
                    const int c = co0 + ln * 4 + ni;
                    float v = fmaxf(acc[mi][ni][r] + bias[c], 0.0f);
                    o.h[ni] = __float2bfloat16(v);
                }
                *(uint2*)(void*)(out + pb + ln * 4) = o.u;
            }
        }
    }
}

// ================= head: 1x1 conv 64->33(pad64) + sigmoid -> bf16 NHWC padded ==========
// Interleaved weights; packed uint2 stores; c>=33 -> 0. FEAT plain 256x256x64.
__global__ __launch_bounds__(256)
void mfma_head_k(const __hip_bfloat16* __restrict__ in,
                 const __hip_bfloat16* __restrict__ wb,
                 const float* __restrict__ hb,
                 __hip_bfloat16* __restrict__ out)
{
    const int tid = threadIdx.x;
    const int wid = tid >> 6, lane = tid & 63;
    const int ln = lane & 15, kg = lane >> 4;
    const int nx = gridDim.x;
    const int bx = (blockIdx.x & 7) * (nx >> 3) + (blockIdx.x >> 3);
    const int u = bx * 4 + wid;
    const int y = u >> 3, x0 = (u & 7) * 32;
    const int b = blockIdx.z;

    f32x4 acc[2][4];
#pragma unroll
    for (int i = 0; i < 2; ++i)
#pragma unroll
        for (int j = 0; j < 4; ++j) acc[i][j] = f32x4{0.f, 0.f, 0.f, 0.f};

    for (int kc = 0; kc < 2; ++kc) {
        const int kofs = kc * 32 + kg * 8;
        bf16x8 wfr[4];
#pragma unroll
        for (int ni = 0; ni < 4; ++ni)
            wfr[ni] = *(const bf16x8*)(const void*)(wb + ((long)(ni * 16 + ln)) * 64 + kofs);
        U16 av[2];
#pragma unroll
        for (int mi = 0; mi < 2; ++mi)
            av[mi].u = *(const uint4*)(const void*)(in + (long)b * 4194304L + ((long)y * 256 + x0 + mi * 16 + ln) * 64 + kofs);
#pragma unroll
        for (int mi = 0; mi < 2; ++mi)
#pragma unroll
            for (int ni = 0; ni < 4; ++ni)
                acc[mi][ni] = __builtin_amdgcn_mfma_f32_16x16x32_bf16(av[mi].v, wfr[ni], acc[mi][ni], 0, 0, 0);
    }
#pragma unroll
    for (int mi = 0; mi < 2; ++mi) {
#pragma unroll
        for (int r = 0; r < 4; ++r) {
            const int px = x0 + mi * 16 + kg * 4 + r;
            const long pb = (long)b * 4260096L + ((long)y * 258 + px) * 64;
            U8 o;
#pragma unroll
            for (int ni = 0; ni < 4; ++ni) {
                const int c = ln * 4 + ni;
                float v = (c < 33) ? sigf(acc[mi][ni][r] + hb[c]) : 0.0f;
                o.h[ni] = __float2bfloat16(v);
            }
            *(uint2*)(void*)(out + pb + ln * 4) = o.u;
        }
    }
}

// ================= refine: 3x3 conv 33(pad64)->33 + bias + rbias + sigmoid -> f32 NCHW =
// Plain weights (NI=3). Block-cooperative epilogue: 512B contiguous NCHW runs,
// channel-staggered per block to decorrelate the 256KB-stride comb.
__global__ __launch_bounds__(256)
void mfma_refine_k(const __hip_bfloat16* __restrict__ in,   // HDI padded interior
                   const __hip_bfloat16* __restrict__ wb,   // [9][64][64] plain
                   const float* __restrict__ cbias, const float* __restrict__ ebias,
                   float* __restrict__ out_f32)
{
    extern __shared__ float ltr[];  // 4 waves x 48ch x 35 f32
    const int tid = threadIdx.x;
    const int wid = tid >> 6, lane = tid & 63;
    const int ln = lane & 15, kg = lane >> 4;
    const int nx = gridDim.x;
    const int bx = (blockIdx.x & 7) * (nx >> 3) + (blockIdx.x >> 3);
    const int u = bx * 4 + wid;
    const int y = u >> 3, x0 = (u & 7) * 32;
    const int b = blockIdx.z;

    f32x4 acc[2][3];
#pragma unroll
    for (int i = 0; i < 2; ++i)
#pragma unroll
        for (int j = 0; j < 3; ++j) acc[i][j] = f32x4{0.f, 0.f, 0.f, 0.f};

    for (int kc = 0; kc < 2; ++kc) {
        const int kofs = kc * 32 + kg * 8;
#pragma unroll
        for (int t = 0; t < 9; ++t) {
            const int dy = t / 3 - 1, dx = t % 3 - 1;
            bf16x8 wfr[3];
#pragma unroll
            for (int ni = 0; ni < 3; ++ni)
                wfr[ni] = *(const bf16x8*)(const void*)(wb + ((long)t * 64 + ni * 16 + ln) * 64 + kofs);
            U16 av[2];
            const long rowb = (long)b * 4260096L + (long)(y + dy) * 258 * 64 + kofs;
#pragma unroll
            for (int mi = 0; mi < 2; ++mi)
                av[mi].u = *(const uint4*)(const void*)(in + rowb + (long)(x0 + mi * 16 + ln + dx) * 64);
#pragma unroll
            for (int mi = 0; mi < 2; ++mi)
#pragma unroll
                for (int ni = 0; ni < 3; ++ni)
                    acc[mi][ni] = __builtin_amdgcn_mfma_f32_16x16x32_bf16(av[mi].v, wfr[ni], acc[mi][ni], 0, 0, 0);
        }
    }

    float* wt = ltr + wid * 1680;  // 48*35
#pragma unroll
    for (int mi = 0; mi < 2; ++mi) {
#pragma unroll
        for (int r = 0; r < 4; ++r) {
            const int pxl = mi * 16 + kg * 4 + r;
#pragma unroll
            for (int ni = 0; ni < 3; ++ni) {
                const int c = ni * 16 + ln;
                float eb = (c < 33) ? (cbias[c] + ebias[b * 33 + c]) : 0.0f;
                wt[c * 35 + pxl] = sigf(acc[mi][ni][r] + eb);
            }
        }
    }
    __syncthreads();
    // block covers 128 px of row yb starting at xb
    const int yb = (bx * 4) >> 3;
    const int xb = ((bx * 4) & 7) * 32;
    const int coff = bx % 33;
    for (int i = tid; i < 4224; i += 256) {   // 33ch x 128px
        int cl = i >> 7, p = i & 127;
        int c = cl + coff; if (c >= 33) c -= 33;
        float v = ltr[(p >> 5) * 1680 + c * 35 + (p & 31)];
        out_f32[((long)b * 33 + c) * 65536L + (long)yb * 256 + xb + p] = v;
    }
}

// ================= maxpool 2x2 on bf16 NHWC (padded-interior output) =================
__global__ __launch_bounds__(256)
void maxpool_bf_k(const __hip_bfloat16* __restrict__ in, __hip_bfloat16* __restrict__ out,
                  int Ho, int Wo, int C, long total, int OPIT, long obstride)
{
    long idx = (long)blockIdx.x * 256 + threadIdx.x;
    if (idx >= total) return;
    const int ng = C >> 3;
    const int cg = (int)(idx % ng);
    long pix = idx / ng;
    const int xo = (int)(pix % Wo); pix /= Wo;
    const int yo = (int)(pix % Ho);
    const int b = (int)(pix / Ho);
    const int Wi = Wo * 2;
    const __hip_bfloat16* p = in + (((long)b * 2 * Ho + 2 * yo) * Wi + 2 * xo) * C + cg * 8;
    U16 a0, a1, a2, a3, o;
    a0.u = *(const uint4*)(const void*)p;
    a1.u = *(const uint4*)(const void*)(p + C);
    a2.u = *(const uint4*)(const void*)(p + (long)Wi * C);
    a3.u = *(const uint4*)(const void*)(p + (long)Wi * C + C);
#pragma unroll
    for (int j = 0; j < 8; ++j) {
        float m = fmaxf(fmaxf(__bfloat162float(a0.h[j]), __bfloat162float(a1.h[j])),
                        fmaxf(__bfloat162float(a2.h[j]), __bfloat162float(a3.h[j])));
        o.h[j] = __float2bfloat16(m);
    }
    *(uint4*)(void*)(out + (long)b * obstride + ((long)yo * OPIT + xo) * C + cg * 8) = o.u;
}

// ================= soft-argmax over bf16 NHWC padded heatmap =================
// Block per (b, 8-channel group). Coalesced uint4 loads; two-pass max + exp-sums.
__global__ __launch_bounds__(256)
void softargmax_nhwc_k(const __hip_bfloat16* __restrict__ hd, float* __restrict__ coords)
{
    __shared__ float sm[8][256];
    __shared__ float fin[8][4];   // m, s, sx, sy
    const int b = blockIdx.x, jg = blockIdx.y;
    const int tid = threadIdx.x;
    const __hip_bfloat16* base = hd + (long)b * 4260096L + jg * 8;
    float m[8];
#pragma unroll
    for (int c = 0; c < 8; ++c) m[c] = -1e30f;
    for (int i = tid; i < 65536; i += 256) {
        int y = i >> 8, x = i & 255;
        U16 v; v.u = *(const uint4*)(const void*)(base + ((long)y * 258 + x) * 64);
#pragma unroll
        for (int c = 0; c < 8; ++c) m[c] = fmaxf(m[c], __bfloat162float(v.h[c]));
    }
#pragma unroll
    for (int c = 0; c < 8; ++c) sm[c][tid] = m[c];
    __syncthreads();
    for (int s = 128; s > 0; s >>= 1) {
        if (tid < s)
#pragma unroll
            for (int c = 0; c < 8; ++c) sm[c][tid] = fmaxf(sm[c][tid], sm[c][tid + s]);
        __syncthreads();
    }
    if (tid < 8) fin[tid][0] = sm[tid][0];
    __syncthreads();
#pragma unroll
    for (int c = 0; c < 8; ++c) m[c] = fin[c][0];
    float s8[8], sx8[8], sy8[8];
#pragma unroll
    for (int c = 0; c < 8; ++c) { s8[c] = 0.f; sx8[c] = 0.f; sy8[c] = 0.f; }
    for (int i = tid; i < 65536; i += 256) {
        int y = i >> 8, x = i & 255;
        U16 v; v.u = *(const uint4*)(const void*)(base + ((long)y * 258 + x) * 64);
#pragma unroll
        for (int c = 0; c < 8; ++c) {
            float e = expf((__bfloat162float(v.h[c]) - m[c]) * 10.0f);
            s8[c] += e; sx8[c] += e * (float)x; sy8[c] += e * (float)y;
        }
    }
    for (int which = 0; which < 3; ++which) {
        __syncthreads();
#pragma unroll
        for (int c = 0; c < 8; ++c)
            sm[c][tid] = (which == 0) ? s8[c] : (which == 1) ? sx8[c] : sy8[c];
        __syncthreads();
        for (int s = 128; s > 0; s >>= 1) {
            if (tid < s)
#pragma unroll
                for (int c = 0; c < 8; ++c) sm[c][tid] += sm[c][tid + s];
            __syncthreads();
        }
        if (tid < 8) fin[tid][1 + which] = sm[tid][0];
    }
    __syncthreads();
    if (tid < 8) {
        int j = jg * 8 + tid;
        if (j < 33) {
            coords[2 * (b * 33 + j)]     = fin[tid][2] / fin[tid][1];
            coords[2 * (b * 33 + j) + 1] = fin[tid][3] / fin[tid][1];
        }
    }
}

// ================= bilinear sample (bf16 NHWC feat) + proj =================
__global__ __launch_bounds__(64)
void joint_bf_k(const __hip_bfloat16* __restrict__ fm, const float* __restrict__ coords,
                const float* __restrict__ pw, const float* __restrict__ pb,
                float* __restrict__ jf)
{
    __shared__ float sj[64];
    const int bj = blockIdx.x, b = bj / 33;
    const int tid = threadIdx.x;
    float ix = coords[2 * bj], iy = coords[2 * bj + 1];
    float x0f = fminf(fmaxf(floorf(ix), 0.0f), 255.0f);
    float y0f = fminf(fmaxf(floorf(iy), 0.0f), 255.0f);
    float wx = ix - x0f, wy = iy - y0f;
    int x0 = (int)x0f, y0 = (int)y0f;
    int x1 = min(x0 + 1, 255), y1 = min(y0 + 1, 255);
    const __hip_bfloat16* base = fm + (long)b * 65536 * 64 + tid;
    float v00 = __bfloat162float(base[((long)y0 * 256 + x0) * 64]);
    float v01 = __bfloat162float(base[((long)y0 * 256 + x1) * 64]);
    float v10 = __bfloat162float(base[((long)y1 * 256 + x0) * 64]);
    float v11 = __bfloat162float(base[((long)y1 * 256 + x1) * 64]);
    sj[tid] = v00 * (1 - wx) * (1 - wy) + v01 * wx * (1 - wy)
            + v10 * (1 - wx) * wy + v11 * wx * wy;
    __syncthreads();
    float a = pb[tid];
    for (int k = 0; k < 64; ++k) a = fmaf(sj[k], pw[tid * 64 + k], a);
    jf[(long)bj * 64 + tid] = a;
}

// ================= graph message + GRU =================
__device__ const int d_nbr[33][4] = {
    {0,0,0,0},{1,0,0,0},{2,0,0,0},{3,0,0,0},{4,0,0,0},{5,0,0,0},{6,0,0,0},{7,0,0,0},
    {8,0,0,0},{9,0,0,0},{10,0,0,0},
    {11,12,23,13},{12,11,24,14},{13,11,15,0},{14,12,16,0},{15,13,0,0},{16,14,0,0},
    {17,0,0,0},{18,0,0,0},{19,0,0,0},{20,0,0,0},{21,0,0,0},{22,0,0,0},
    {23,11,24,25},{24,12,23,26},{25,23,27,0},{26,24,28,0},{27,25,0,0},{28,26,0,0},
    {29,0,0,0},{30,0,0,0},{31,0,0,0},{32,0,0,0}};
__device__ const int d_cnt[33] = {1,1,1,1,1,1,1,1,1,1,1,4,4,3,3,2,2,1,1,1,1,1,1,4,4,3,3,2,2,1,1,1,1};

__global__ __launch_bounds__(192)
void gru_k(const float* __restrict__ jf, const float* __restrict__ mw, const float* __restrict__ mb,
           const float* __restrict__ wih, const float* __restrict__ whh,
           const float* __restrict__ bih, const float* __restrict__ bhh,
           float* __restrict__ rbias)
{
    __shared__ float s_mjf[64], s_jf[64], s_msg[64], s_gi[192], s_gh[192], s_ref[64];
    const int bj = blockIdx.x;
    const int b = bj / 33, j = bj % 33;
    const int tid = threadIdx.x;
    if (tid < 64) {
        int cnt = d_cnt[j];
        float s = 0.0f;
        for (int n = 0; n < 4; ++n)
            if (n < cnt) s += jf[((long)b * 33 + d_nbr[j][n]) * 64 + tid];
        s_mjf[tid] = s / (float)cnt;
        s_jf[tid] = jf[(long)bj * 64 + tid];
    }
    __syncthreads();
    if (tid < 64) {
        float a = mb[tid];
        for (int k = 0; k < 64; ++k) a = fmaf(mw[tid * 64 + k], s_mjf[k], a);
        s_msg[tid] = a;
    }
    __syncthreads();
    {
        float a = bih[tid], c = bhh[tid];
        for (int k = 0; k < 64; ++k) {
            a = fmaf(wih[tid * 64 + k], s_msg[k], a);
            c = fmaf(whh[tid * 64 + k], s_jf[k], c);
        }
        s_gi[tid] = a; s_gh[tid] = c;
    }
    __syncthreads();
    if (tid < 64) {
        float r = sigf(s_gi[tid] + s_gh[tid]);
        float z = sigf(s_gi[64 + tid] + s_gh[64 + tid]);
        float n = tanhf(s_gi[128 + tid] + r * s_gh[128 + tid]);
        s_ref[tid] = (1.0f - z) * n + z * s_jf[tid];
    }
    __syncthreads();
    if (tid == 0) {
        float s = 0.0f;
        for (int k = 0; k < 64; ++k) s += s_ref[k];
        rbias[bj] = s * (1.0f / 64.0f);
    }
}

// ================= vis branch =================
__global__ __launch_bounds__(256)
void vispool_bf_k(const __hip_bfloat16* __restrict__ enc, float* __restrict__ p)
{
    int idx = blockIdx.x * 256 + threadIdx.x;  // 65536
    int v = idx & 3, uu = (idx >> 2) & 3, c = (idx >> 4) & 255, b = idx >> 12;
    const __hip_bfloat16* base = enc + (long)b * 64 * 64 * 256 + c;
    float s = 0.0f;
    for (int a = 0; a < 16; ++a)
#pragma unroll
        for (int d = 0; d < 16; ++d)
            s += __bfloat162float(base[((long)(uu * 16 + a) * 64 + (v * 16 + d)) * 256]);
    p[idx] = s * (1.0f / 256.0f);
}

__global__ __launch_bounds__(256)
void visfc1_k(const float* __restrict__ p, const float* __restrict__ w1,
              const float* __restrict__ b1, float* __restrict__ v1)
{
    __shared__ float s_p[4096];
    const int b = blockIdx.x, tid = threadIdx.x;
    for (int i = tid; i < 4096; i += 256) s_p[i] = p[b * 4096 + i];
    __syncthreads();
    float a = b1[tid];
    const float* wr = w1 + (long)tid * 4096;
    for (int k = 0; k < 4096; ++k) a = fmaf(wr[k], s_p[k], a);
    v1[b * 256 + tid] = fmaxf(a, 0.0f);
}

__global__ __launch_bounds__(64)
void visfc2_k(const float* __restrict__ v1, const float* __restrict__ w2,
              const float* __restrict__ b2, float* __restrict__ out)
{
    const int b = blockIdx.x, t = threadIdx.x;
    if (t < 33) {
        float a = b2[t];
        for (int k = 0; k < 256; ++k) a = fmaf(w2[t * 256 + k], v1[b * 256 + k], a);
        out[b * 33 + t] = sigf(a);
    }
}

extern "C" void kernel_launch(void* const* d_in, const int* in_sizes, int n_in,
                              void* d_out, int out_size, void* d_ws, size_t ws_size,
                              hipStream_t stream)
{
    const float* x   = (const float*)d_in[0];
    const float* c1w = (const float*)d_in[1];  const float* c1b = (const float*)d_in[2];
    const float* b1g = (const float*)d_in[3];  const float* b1b = (const float*)d_in[4];
    const float* c2w = (const float*)d_in[5];  const float* c2b = (const float*)d_in[6];
    const float* b2g = (const float*)d_in[7];  const float* b2b = (const float*)d_in[8];
    const float* c3w = (const float*)d_in[9];  const float* c3b = (const float*)d_in[10];
    const float* b3g = (const float*)d_in[11]; const float* b3b = (const float*)d_in[12];
    const float* c4w = (const float*)d_in[13]; const float* c4b = (const float*)d_in[14];
    const float* b4g = (const float*)d_in[15]; const float* b4b = (const float*)d_in[16];
    const float* d1w = (const float*)d_in[17]; const float* d1b = (const float*)d_in[18];
    const float* d2w = (const float*)d_in[19]; const float* d2b = (const float*)d_in[20];
    const float* hw  = (const float*)d_in[21]; const float* hb  = (const float*)d_in[22];
    const float* pw  = (const float*)d_in[23]; const float* pb  = (const float*)d_in[24];
    const float* mw  = (const float*)d_in[25]; const float* mb  = (const float*)d_in[26];
    const float* wih = (const float*)d_in[27]; const float* whh = (const float*)d_in[28];
    const float* bih = (const float*)d_in[29]; const float* bhh = (const float*)d_in[30];
    const float* rw  = (const float*)d_in[31]; const float* rb  = (const float*)d_in[32];
    const float* v1w = (const float*)d_in[33]; const float* v1b = (const float*)d_in[34];
    const float* v2w = (const float*)d_in[35]; const float* v2b = (const float*)d_in[36];

    // ---- lifetime-packed workspace ----
    char* ws = (char*)d_ws;
    __hip_bfloat16* ENC  = (__hip_bfloat16*)(ws + 0L);             // [conv4..vis]
    __hip_bfloat16* R1   = (__hip_bfloat16*)(ws + 33554432L);      // H1 -> P1 -> FEAT
    __hip_bfloat16* R2   = (__hip_bfloat16*)(ws + 167772160L);     // H3 -> F -> HEADB
    char*           R3c  = ws + 304095232L;                        // P2
    char* SM = ws + 442507264L;

    __hip_bfloat16* H1B = R1;                 __hip_bfloat16* H1I = R1 + 8288;    // 258p,C32
    __hip_bfloat16* P1B = R1;                 __hip_bfloat16* P1I = R1 + 8384;    // 130p,C64
    __hip_bfloat16* FEAT = R1;                                                    // 256,C64 plain
    __hip_bfloat16* H3  = R2;                                                     // 128,C128 plain
    __hip_bfloat16* F   = R2;                                                     // 128,C128 plain
    __hip_bfloat16* HDB = R2;                 __hip_bfloat16* HDI = R2 + 16576;   // 258p,C64
    __hip_bfloat16* P2B = (__hip_bfloat16*)R3c; __hip_bfloat16* P2I = P2B + 8576; // 66p,C128

    __hip_bfloat16* W2B = (__hip_bfloat16*)(SM + 0);
    __hip_bfloat16* W3B = (__hip_bfloat16*)(SM + 36864);
    __hip_bfloat16* W4B = (__hip_bfloat16*)(SM + 184320);
    __hip_bfloat16* WRB = (__hip_bfloat16*)(SM + 774144);
    __hip_bfloat16* WHB = (__hip_bfloat16*)(SM + 847872);
    __hip_bfloat16* WD1 = (__hip_bfloat16*)(SM + 856064);
    __hip_bfloat16* WD2 = (__hip_bfloat16*)(SM + 1118208);
    float* CO = (float*)(SM + 1183744);
    float* JF = (float*)(SM + 1187968);
    float* RB = (float*)(SM + 1323136);
    float* P  = (float*)(SM + 1325248);
    float* V1 = (float*)(SM + 1587392);

    float* out_hm  = (float*)d_out;        // (16,33,256,256)
    float* out_vis = out_hm + 34603008L;   // (16,33)
    __hip_bfloat16* H2 = (__hip_bfloat16*)d_out;  // scratch: conv2 out, dead before refine

    // ---- weight repacks ----
    repack_conv_w_ilv_k<<<(9*64*32 + 255)/256, 256, 0, stream>>>(c2w, W2B, 9, 64, 32, 64, 32);
    repack_conv_w_ilv_k<<<(9*128*64 + 255)/256, 256, 0, stream>>>(c3w, W3B, 9, 128, 64, 128, 64);
    repack_conv_w_ilv_k<<<(9*256*128 + 255)/256, 256, 0, stream>>>(c4w, W4B, 9, 256, 128, 256, 128);
    repack_conv_w_k<<<(9*64*64 + 255)/256, 256, 0, stream>>>(rw, WRB, 9, 33, 33, 64, 64);
    repack_conv_w_ilv_k<<<(1*64*64 + 255)/256, 256, 0, stream>>>(hw, WHB, 1, 33, 64, 64, 64);
    repack_deconv_w_ilv_k<<<(4*128*256 + 255)/256, 256, 0, stream>>>(d1w, WD1, 128, 256);
    repack_deconv_w_ilv_k<<<(4*64*128 + 255)/256, 256, 0, stream>>>(d2w, WD2, 64, 128);

    // halo zeroing
    zero_halo_k<<<(526336 + 255)/256, 256, 0, stream>>>(H1B, 256, 256, 32, 16);
    zero_halo_k<<<(532480 + 255)/256, 256, 0, stream>>>(P2B, 64, 64, 128, 16);

    // 1) conv1 3->32 @256 -> H1 (padded)
    conv1_k<<<dim3(4, 16, 64), 256, 0, stream>>>(x, c1w, c1b, b1g, b1b, H1I);
    // 2) conv2 32->64 @256 -> H2 (d_out scratch)
    mfma_conv_k<2><<<dim3(512, 1, 16), 256, 0, stream>>>(
        H1I, W2B, c2b, b2g, b2b, H2,
        256, 256, 32, 258, 2130048L, 4194304L, 256, 64, 1, 8);
    // 3) pool -> P1 (padded)
    zero_halo_k<<<(528384 + 255)/256, 256, 0, stream>>>(P1B, 128, 128, 64, 16);
    maxpool_bf_k<<<8192, 256, 0, stream>>>(H2, P1I, 128, 128, 64, 2097152L, 130, 1081600L);
    // 4) conv3 64->128 @128 -> H3
    mfma_conv_k<2><<<dim3(128, 1, 32), 256, 0, stream>>>(
        P1I, W3B, c3b, b3g, b3b, H3,
        128, 128, 64, 130, 1081600L, 2097152L, 128, 128, 2, 4);
    // 5) pool -> P2 (padded)
    maxpool_bf_k<<<4096, 256, 0, stream>>>(H3, P2I, 64, 64, 128, 1048576L, 66, 557568L);
    // 6) conv4 128->256 @64 -> ENC
    mfma_conv_k<2><<<dim3(32, 1, 64), 256, 0, stream>>>(
        P2I, W4B, c4b, b4g, b4b, ENC,
        64, 64, 128, 66, 557568L, 1048576L, 64, 256, 4, 2);
    // 7) dc1 256->128 (64->128 up) -> F
    mfma_deconv_k<<<dim3(32, 1, 32), 256, 0, stream>>>(
        ENC, WD1, d1b, F, 64, 64, 256, 128, 2, 2);
    // 8) dc2 128->64 (128->256 up) -> FEAT
    mfma_deconv_k<<<dim3(128, 1, 16), 256, 0, stream>>>(
        F, WD2, d2b, FEAT, 128, 128, 128, 64, 1, 4);
    // 9) head 1x1 + sigmoid -> HDI (padded bf16 NHWC only; no f32 heatmap)
    zero_halo_k<<<(1052672 + 255)/256, 256, 0, stream>>>(HDB, 256, 256, 64, 16);
    mfma_head_k<<<dim3(512, 1, 16), 256, 0, stream>>>(FEAT, WHB, hb, HDI);
    // 10) soft-argmax over bf16 NHWC heatmap
    softargmax_nhwc_k<<<dim3(16, 5), 256, 0, stream>>>(HDI, CO);
    // 11) bilinear + proj
    joint_bf_k<<<528, 64, 0, stream>>>(FEAT, CO, pw, pb, JF);
    // 12) message + GRU -> refined_bias
    gru_k<<<528, 192, 0, stream>>>(JF, mw, mb, wih, whh, bih, bhh, RB);
    // 13) refine 33->33 @256 + bias + sigmoid -> out_hm (f32 nchw, cooperative stores)
    mfma_refine_k<<<dim3(512, 1, 16), 256, 26880, stream>>>(
        HDI, WRB, rb, RB, out_hm);
    // 14) vis pool -> P (16,4096)
    vispool_bf_k<<<256, 256, 0, stream>>>(ENC, P);
    // 15) fc1 + relu
    visfc1_k<<<16, 256, 0, stream>>>(P, v1w, v1b, V1);
    // 16) fc2 + sigmoid
    visfc2_k<<<16, 64, 0, stream>>>(V1, v2w, v2b, out_vis);
}

// Round 17
// 1622.505 us; speedup vs baseline: 1.1437x; 1.1437x over previous
//
#include <hip/hip_runtime.h>
#include <hip/hip_bf16.h>
#include <math.h>

#define BN_RS 0.99999500003749977f  // 1/sqrt(1 + 1e-5)

typedef __attribute__((ext_vector_type(8))) __bf16 bf16x8;
typedef __attribute__((ext_vector_type(4))) float f32x4;

union U16 { uint4 u; bf16x8 v; __hip_bfloat16 h[8]; };
union U8  { uint2 u; __hip_bfloat16 h[4]; };

__device__ __forceinline__ float sigf(float v) { return 1.0f / (1.0f + expf(-v)); }

// ================= weight repack =================
__global__ __launch_bounds__(256)
void repack_conv_w_k(const float* __restrict__ w, __hip_bfloat16* __restrict__ wb,
                     int taps, int Co, int Ci, int CoT, int Kp)
{
    int i = blockIdx.x * 256 + threadIdx.x;
    int tot = taps * CoT * Kp;
    if (i >= tot) return;
    int k = i % Kp, n = (i / Kp) % CoT, t = i / (Kp * CoT);
    float v = (n < Co && k < Ci) ? w[((long)n * Ci + k) * taps + t] : 0.0f;
    wb[i] = __float2bfloat16(v);
}
__global__ __launch_bounds__(256)
void repack_conv_w_ilv_k(const float* __restrict__ w, __hip_bfloat16* __restrict__ wb,
                         int taps, int Co, int Ci, int CoT, int Kp)
{
    int i = blockIdx.x * 256 + threadIdx.x;
    int tot = taps * CoT * Kp;
    if (i >= tot) return;
    int k = i % Kp, n = (i / Kp) % CoT, t = i / (Kp * CoT);
    int grp = n >> 6, r = n & 63;
    int c = (grp << 6) + (r & 15) * 4 + (r >> 4);
    float v = (c < Co && k < Ci) ? w[((long)c * Ci + k) * taps + t] : 0.0f;
    wb[i] = __float2bfloat16(v);
}
__global__ __launch_bounds__(256)
void repack_deconv_w_ilv_k(const float* __restrict__ w, __hip_bfloat16* __restrict__ wb,
                           int Co, int Ci)
{
    int i = blockIdx.x * 256 + threadIdx.x;
    int tot = 4 * Co * Ci;
    if (i >= tot) return;
    int k = i % Ci, n = (i / Ci) % Co, q = i / (Ci * Co);
    int grp = n >> 6, r = n & 63;
    int c = (grp << 6) + (r & 15) * 4 + (r >> 4);
    wb[i] = __float2bfloat16(w[((long)k * Co + c) * 4 + q]);
}

// ================= zero the 1-px halo of a padded NHWC buffer =================
__global__ __launch_bounds__(256)
void zero_halo_k(__hip_bfloat16* __restrict__ buf, int H, int W, int C, int B)
{
    const int P = W + 2;
    const long per = (long)(2 * P + 2 * H) * C;
    long idx = (long)blockIdx.x * 256 + threadIdx.x;
    if (idx >= per * B) return;
    int b = (int)(idx / per);
    long r = idx % per;
    long off;
    if (r < (long)2 * P * C) {
        int row = (r >= (long)P * C) ? (H + 1) : 0;
        long r2 = r % ((long)P * C);
        off = (((long)b * (H + 2) + row) * P) * C + r2;
    } else {
        long r2 = r - (long)2 * P * C;
        int row = 1 + (int)(r2 / (2 * C));
        int side = (int)((r2 / C) & 1);
        int ch = (int)(r2 % C);
        off = (((long)b * (H + 2) + row) * P + (side ? (W + 1) : 0)) * C + ch;
    }
    buf[off] = __float2bfloat16(0.0f);
}

// ================= conv1 (3->32, scalar fp32, writes bf16 NHWC padded-interior) =================
__global__ __launch_bounds__(256)
void conv1_k(const float* __restrict__ x, const float* __restrict__ w,
             const float* __restrict__ cb, const float* __restrict__ g,
             const float* __restrict__ bb, __hip_bfloat16* __restrict__ out)
{
    __shared__ float sw[216];
    const int tid = threadIdx.x;
    const int b = blockIdx.z >> 2, cg = blockIdx.z & 3, co0 = cg * 8;
    for (int i = tid; i < 216; i += 256) {
        int t = i % 9, co = (i / 9) % 8, ci = i / 72;
        sw[i] = w[((co0 + co) * 3 + ci) * 9 + t];
    }
    __syncthreads();
    const int tx = tid & 15, ty = tid >> 4;
    const int y = blockIdx.y * 16 + ty;
    const int xs = blockIdx.x * 64 + tx;
    float acc[4][8];
#pragma unroll
    for (int p = 0; p < 4; ++p)
#pragma unroll
        for (int c = 0; c < 8; ++c) acc[p][c] = 0.0f;
    for (int ci = 0; ci < 3; ++ci) {
        const float* plane = x + ((long)b * 3 + ci) * 65536;
#pragma unroll
        for (int t = 0; t < 9; ++t) {
            const int dy = t / 3 - 1, dx = t % 3 - 1;
            const int yy = y + dy;
            if ((unsigned)yy < 256u) {
                const float* row = plane + yy * 256;
                float wsr[8];
#pragma unroll
                for (int c = 0; c < 8; ++c) wsr[c] = sw[ci * 72 + c * 9 + t];
#pragma unroll
                for (int p = 0; p < 4; ++p) {
                    const int xx = xs + p * 16 + dx;
                    const float v = ((unsigned)xx < 256u) ? row[xx] : 0.0f;
#pragma unroll
                    for (int c = 0; c < 8; ++c) acc[p][c] = fmaf(v, wsr[c], acc[p][c]);
                }
            }
        }
    }
#pragma unroll
    for (int p = 0; p < 4; ++p) {
        U16 o;
#pragma unroll
        for (int c = 0; c < 8; ++c) {
            const int cc = co0 + c;
            float v = fmaxf(acc[p][c] + cb[cc], 0.0f) * (g[cc] * BN_RS) + bb[cc];
            o.h[c] = __float2bfloat16(v);
        }
        *(uint4*)(void*)(out + ((long)b * 2130048L + ((long)y * 258 + xs + p * 16) * 32) + co0) = o.u;
    }
}

// ================= MFMA conv 3x3 (implicit GEMM, halo-padded input) =================
template<int MI>
__global__ __launch_bounds__(256)
void mfma_conv_k(const __hip_bfloat16* __restrict__ in,
                 const __hip_bfloat16* __restrict__ wb,
                 const float* __restrict__ cbias,
                 const float* __restrict__ bng, const float* __restrict__ bnb,
                 __hip_bfloat16* __restrict__ out_bf,
                 int H, int W, int Cin, int PIT, long bstride, long obstride, int OPIT,
                 int CoutT, int CG, int S)
{
    const int tid = threadIdx.x;
    const int wid = tid >> 6, lane = tid & 63;
    const int ln = lane & 15, kg = lane >> 4;
    const int nx = gridDim.x;
    const int bx = (blockIdx.x & 7) * (nx >> 3) + (blockIdx.x >> 3);
    const int u = bx * 4 + wid;
    const int y = u / S, x0 = (u % S) * (MI * 16);
    const int b = blockIdx.z / CG, cg = blockIdx.z % CG;
    const int co0 = cg * 64;
    const int KC = Cin >> 5;

    f32x4 acc[MI][4];
#pragma unroll
    for (int i = 0; i < MI; ++i)
#pragma unroll
        for (int j = 0; j < 4; ++j) acc[i][j] = f32x4{0.f, 0.f, 0.f, 0.f};

    for (int kc = 0; kc < KC; ++kc) {
        const int kofs = kc * 32 + kg * 8;
#pragma unroll
        for (int t = 0; t < 9; ++t) {
            const int dy = t / 3 - 1, dx = t % 3 - 1;
            bf16x8 wfr[4];
#pragma unroll
            for (int ni = 0; ni < 4; ++ni)
                wfr[ni] = *(const bf16x8*)(const void*)(wb + ((long)t * CoutT + co0 + ni * 16 + ln) * Cin + kofs);
            U16 av[MI];
            const long rowb = (long)b * bstride + (long)(y + dy) * PIT * Cin + kofs;
#pragma unroll
            for (int mi = 0; mi < MI; ++mi)
                av[mi].u = *(const uint4*)(const void*)(in + rowb + (long)(x0 + mi * 16 + ln + dx) * Cin);
#pragma unroll
            for (int mi = 0; mi < MI; ++mi)
#pragma unroll
                for (int ni = 0; ni < 4; ++ni)
                    acc[mi][ni] = __builtin_amdgcn_mfma_f32_16x16x32_bf16(av[mi].v, wfr[ni], acc[mi][ni], 0, 0, 0);
        }
    }
#pragma unroll
    for (int mi = 0; mi < MI; ++mi) {
#pragma unroll
        for (int r = 0; r < 4; ++r) {
            const int px = x0 + mi * 16 + kg * 4 + r;
            const long pb = (long)b * obstride + ((long)y * OPIT + px) * CoutT + co0;
            U8 o;
#pragma unroll
            for (int ni = 0; ni < 4; ++ni) {
                const int c = co0 + ln * 4 + ni;
                float v = acc[mi][ni][r] + cbias[c];
                v = fmaxf(v, 0.0f) * (bng[c] * BN_RS) + bnb[c];
                o.h[ni] = __float2bfloat16(v);
            }
            *(uint2*)(void*)(out_bf + pb + ln * 4) = o.u;
        }
    }
}

// ================= MFMA deconv 2x2 + ReLU (interleaved weights, packed stores) =========
__global__ __launch_bounds__(256)
void mfma_deconv_k(const __hip_bfloat16* __restrict__ in,
                   const __hip_bfloat16* __restrict__ wb,
                   const float* __restrict__ bias,
                   __hip_bfloat16* __restrict__ out,
                   int H, int W, int Cin, int CoutT, int CG, int S)
{
    const int tid = threadIdx.x;
    const int wid = tid >> 6, lane = tid & 63;
    const int ln = lane & 15, kg = lane >> 4;
    const int nx = gridDim.x;
    const int bx = (blockIdx.x & 7) * (nx >> 3) + (blockIdx.x >> 3);
    const int u = bx * 4 + wid;
    const int y = u / S, x0 = (u % S) * 32;
    const int b = blockIdx.z / CG, cg = blockIdx.z % CG;
    const int co0 = cg * 64;
    const int KC = Cin >> 5;
    const long inb = (long)b * H * W * Cin;
    const int W2 = W * 2;
    const long ob = (long)b * 4 * H * W * CoutT;

    for (int q = 0; q < 4; ++q) {
        const int dy = q >> 1, dx = q & 1;
        f32x4 acc[2][4];
#pragma unroll
        for (int i = 0; i < 2; ++i)
#pragma unroll
            for (int j = 0; j < 4; ++j) acc[i][j] = f32x4{0.f, 0.f, 0.f, 0.f};
        for (int kc = 0; kc < KC; ++kc) {
            const int kofs = kc * 32 + kg * 8;
            bf16x8 wfr[4];
            U16 av[2];
#pragma unroll
            for (int ni = 0; ni < 4; ++ni)
                wfr[ni] = *(const bf16x8*)(const void*)(wb + ((long)q * CoutT + co0 + ni * 16 + ln) * Cin + kofs);
#pragma unroll
            for (int mi = 0; mi < 2; ++mi)
                av[mi].u = *(const uint4*)(const void*)(in + inb + ((long)y * W + x0 + mi * 16 + ln) * Cin + kofs);
#pragma unroll
            for (int mi = 0; mi < 2; ++mi)
#pragma unroll
                for (int ni = 0; ni < 4; ++ni)
                    acc[mi][ni] = __builtin_amdgcn_mfma_f32_16x16x32_bf16(av[mi].v, wfr[ni], acc[mi][ni], 0, 0, 0);
        }
#pragma unroll
        for (int mi = 0; mi < 2; ++mi) {
#pragma unroll
            for (int r = 0; r < 4; ++r) {
                const int xl = x0 + mi * 16 + kg * 4 + r;
                const long pb = ob + ((long)(2 * y + dy) * W2 + 2 * xl + dx) * CoutT + co0;
                U8 o;
#pragma unroll
                for (int ni = 0; ni < 4; ++ni) {
                    const int c = co0 + ln * 4 + ni;
                    float v = fmaxf(acc[mi][ni][r] + bias[c], 0.0f);
                    o.h[ni] = __float2bfloat16(v);
                }
                *(uint2*)(void*)(out + pb + ln * 4) = o.u;
            }
        }
    }
}

// ================= head: 1x1 conv 64->33(pad64) + sigmoid -> bf16 NHWC padded ==========
__global__ __launch_bounds__(256)
void mfma_head_k(const __hip_bfloat16* __restrict__ in,
                 const __hip_bfloat16* __restrict__ wb,
                 const float* __restrict__ hb,
                 __hip_bfloat16* __restrict__ out)
{
    const int tid = threadIdx.x;
    const int wid = tid >> 6, lane = tid & 63;
    const int ln = lane & 15, kg = lane >> 4;
    const int nx = gridDim.x;
    const int bx = (blockIdx.x & 7) * (nx >> 3) + (blockIdx.x >> 3);
    const int u = bx * 4 + wid;
    const int y = u >> 3, x0 = (u & 7) * 32;
    const int b = blockIdx.z;

    f32x4 acc[2][4];
#pragma unroll
    for (int i = 0; i < 2; ++i)
#pragma unroll
        for (int j = 0; j < 4; ++j) acc[i][j] = f32x4{0.f, 0.f, 0.f, 0.f};

    for (int kc = 0; kc < 2; ++kc) {
        const int kofs = kc * 32 + kg * 8;
        bf16x8 wfr[4];
#pragma unroll
        for (int ni = 0; ni < 4; ++ni)
            wfr[ni] = *(const bf16x8*)(const void*)(wb + ((long)(ni * 16 + ln)) * 64 + kofs);
        U16 av[2];
#pragma unroll
        for (int mi = 0; mi < 2; ++mi)
            av[mi].u = *(const uint4*)(const void*)(in + (long)b * 4194304L + ((long)y * 256 + x0 + mi * 16 + ln) * 64 + kofs);
#pragma unroll
        for (int mi = 0; mi < 2; ++mi)
#pragma unroll
            for (int ni = 0; ni < 4; ++ni)
                acc[mi][ni] = __builtin_amdgcn_mfma_f32_16x16x32_bf16(av[mi].v, wfr[ni], acc[mi][ni], 0, 0, 0);
    }
#pragma unroll
    for (int mi = 0; mi < 2; ++mi) {
#pragma unroll
        for (int r = 0; r < 4; ++r) {
            const int px = x0 + mi * 16 + kg * 4 + r;
            const long pb = (long)b * 4260096L + ((long)y * 258 + px) * 64;
            U8 o;
#pragma unroll
            for (int ni = 0; ni < 4; ++ni) {
                const int c = ln * 4 + ni;
                float v = (c < 33) ? sigf(acc[mi][ni][r] + hb[c]) : 0.0f;
                o.h[ni] = __float2bfloat16(v);
            }
            *(uint2*)(void*)(out + pb + ln * 4) = o.u;
        }
    }
}

// ================= refine: 3x3 conv 33(pad64)->33 + bias + rbias + sigmoid -> f32 NCHW =
__global__ __launch_bounds__(256)
void mfma_refine_k(const __hip_bfloat16* __restrict__ in,   // HDI padded interior
                   const __hip_bfloat16* __restrict__ wb,   // [9][64][64] plain
                   const float* __restrict__ cbias, const float* __restrict__ ebias,
                   float* __restrict__ out_f32)
{
    extern __shared__ float ltr[];  // 4 waves x 48ch x 35 f32
    const int tid = threadIdx.x;
    const int wid = tid >> 6, lane = tid & 63;
    const int ln = lane & 15, kg = lane >> 4;
    const int nx = gridDim.x;
    const int bx = (blockIdx.x & 7) * (nx >> 3) + (blockIdx.x >> 3);
    const int u = bx * 4 + wid;
    const int y = u >> 3, x0 = (u & 7) * 32;
    const int b = blockIdx.z;

    f32x4 acc[2][3];
#pragma unroll
    for (int i = 0; i < 2; ++i)
#pragma unroll
        for (int j = 0; j < 3; ++j) acc[i][j] = f32x4{0.f, 0.f, 0.f, 0.f};

    for (int kc = 0; kc < 2; ++kc) {
        const int kofs = kc * 32 + kg * 8;
#pragma unroll
        for (int t = 0; t < 9; ++t) {
            const int dy = t / 3 - 1, dx = t % 3 - 1;
            bf16x8 wfr[3];
#pragma unroll
            for (int ni = 0; ni < 3; ++ni)
                wfr[ni] = *(const bf16x8*)(const void*)(wb + ((long)t * 64 + ni * 16 + ln) * 64 + kofs);
            U16 av[2];
            const long rowb = (long)b * 4260096L + (long)(y + dy) * 258 * 64 + kofs;
#pragma unroll
            for (int mi = 0; mi < 2; ++mi)
                av[mi].u = *(const uint4*)(const void*)(in + rowb + (long)(x0 + mi * 16 + ln + dx) * 64);
#pragma unroll
            for (int mi = 0; mi < 2; ++mi)
#pragma unroll
                for (int ni = 0; ni < 3; ++ni)
                    acc[mi][ni] = __builtin_amdgcn_mfma_f32_16x16x32_bf16(av[mi].v, wfr[ni], acc[mi][ni], 0, 0, 0);
        }
    }

    float* wt = ltr + wid * 1680;  // 48*35
#pragma unroll
    for (int mi = 0; mi < 2; ++mi) {
#pragma unroll
        for (int r = 0; r < 4; ++r) {
            const int pxl = mi * 16 + kg * 4 + r;
#pragma unroll
            for (int ni = 0; ni < 3; ++ni) {
                const int c = ni * 16 + ln;
                float eb = (c < 33) ? (cbias[c] + ebias[b * 33 + c]) : 0.0f;
                wt[c * 35 + pxl] = sigf(acc[mi][ni][r] + eb);
            }
        }
    }
    __syncthreads();
    const int yb = (bx * 4) >> 3;
    const int xb = ((bx * 4) & 7) * 32;
    const int coff = bx % 33;
    for (int i = tid; i < 4224; i += 256) {   // 33ch x 128px
        int cl = i >> 7, p = i & 127;
        int c = cl + coff; if (c >= 33) c -= 33;
        float v = ltr[(p >> 5) * 1680 + c * 35 + (p & 31)];
        out_f32[((long)b * 33 + c) * 65536L + (long)yb * 256 + xb + p] = v;
    }
}

// ================= maxpool 2x2 on bf16 NHWC (padded-interior output) =================
__global__ __launch_bounds__(256)
void maxpool_bf_k(const __hip_bfloat16* __restrict__ in, __hip_bfloat16* __restrict__ out,
                  int Ho, int Wo, int C, long total, int OPIT, long obstride)
{
    long idx = (long)blockIdx.x * 256 + threadIdx.x;
    if (idx >= total) return;
    const int ng = C >> 3;
    const int cg = (int)(idx % ng);
    long pix = idx / ng;
    const int xo = (int)(pix % Wo); pix /= Wo;
    const int yo = (int)(pix % Ho);
    const int b = (int)(pix / Ho);
    const int Wi = Wo * 2;
    const __hip_bfloat16* p = in + (((long)b * 2 * Ho + 2 * yo) * Wi + 2 * xo) * C + cg * 8;
    U16 a0, a1, a2, a3, o;
    a0.u = *(const uint4*)(const void*)p;
    a1.u = *(const uint4*)(const void*)(p + C);
    a2.u = *(const uint4*)(const void*)(p + (long)Wi * C);
    a3.u = *(const uint4*)(const void*)(p + (long)Wi * C + C);
#pragma unroll
    for (int j = 0; j < 8; ++j) {
        float m = fmaxf(fmaxf(__bfloat162float(a0.h[j]), __bfloat162float(a1.h[j])),
                        fmaxf(__bfloat162float(a2.h[j]), __bfloat162float(a3.h[j])));
        o.h[j] = __float2bfloat16(m);
    }
    *(uint4*)(void*)(out + (long)b * obstride + ((long)yo * OPIT + xo) * C + cg * 8) = o.u;
}

// ================= hierarchical soft-argmax over bf16 NHWC padded heatmap =========
__global__ __launch_bounds__(256)
void softargmax_slab_k(const __hip_bfloat16* __restrict__ hd, float* __restrict__ ss)
{
    __shared__ float sm[64 * 33];
    __shared__ float mg[64];
    const int blk = blockIdx.x;
    const int b = blk >> 4, slab = blk & 15;
    const int tid = threadIdx.x;
    const int pxl = tid >> 3, cg = tid & 7;
    const __hip_bfloat16* base = hd + (long)b * 4260096L + (long)(slab * 16) * 258 * 64 + cg * 8;

    float m8[8];
#pragma unroll
    for (int c = 0; c < 8; ++c) m8[c] = -1e30f;
    for (int yy = 0; yy < 16; ++yy)
        for (int xc = 0; xc < 8; ++xc) {
            U16 v; v.u = *(const uint4*)(const void*)(base + ((long)yy * 258 + xc * 32 + pxl) * 64);
#pragma unroll
            for (int c = 0; c < 8; ++c) m8[c] = fmaxf(m8[c], __bfloat162float(v.h[c]));
        }
#pragma unroll
    for (int c = 0; c < 8; ++c) sm[(cg * 8 + c) * 33 + pxl] = m8[c];
    __syncthreads();
    for (int s = 16; s > 0; s >>= 1) {
        if (pxl < s)
#pragma unroll
            for (int c = 0; c < 8; ++c) {
                int a = (cg * 8 + c) * 33;
                sm[a + pxl] = fmaxf(sm[a + pxl], sm[a + pxl + s]);
            }
        __syncthreads();
    }
    if (tid < 64) mg[tid] = sm[tid * 33];
    __syncthreads();
    if (tid < 33) ss[(long)blk * 132 + tid] = mg[tid];
    float mm[8];
#pragma unroll
    for (int c = 0; c < 8; ++c) mm[c] = mg[cg * 8 + c];

    float s8[8], sx8[8], sy8[8];
#pragma unroll
    for (int c = 0; c < 8; ++c) { s8[c] = 0.f; sx8[c] = 0.f; sy8[c] = 0.f; }
    for (int yy = 0; yy < 16; ++yy) {
        const float fy = (float)(slab * 16 + yy);
        for (int xc = 0; xc < 8; ++xc) {
            const int x = xc * 32 + pxl;
            U16 v; v.u = *(const uint4*)(const void*)(base + ((long)yy * 258 + x) * 64);
#pragma unroll
            for (int c = 0; c < 8; ++c) {
                float e = expf((__bfloat162float(v.h[c]) - mm[c]) * 10.0f);
                s8[c] += e; sx8[c] += e * (float)x; sy8[c] += e * fy;
            }
        }
    }
    for (int which = 0; which < 3; ++which) {
        __syncthreads();
#pragma unroll
        for (int c = 0; c < 8; ++c)
            sm[(cg * 8 + c) * 33 + pxl] = (which == 0) ? s8[c] : (which == 1) ? sx8[c] : sy8[c];
        __syncthreads();
        for (int s = 16; s > 0; s >>= 1) {
            if (pxl < s)
#pragma unroll
                for (int c = 0; c < 8; ++c) {
                    int a = (cg * 8 + c) * 33;
                    sm[a + pxl] += sm[a + pxl + s];
                }
            __syncthreads();
        }
        if (tid < 33) ss[(long)blk * 132 + (which + 1) * 33 + tid] = sm[tid * 33];
    }
}

__global__ __launch_bounds__(64)
void softargmax_comb_k(const float* __restrict__ ss, float* __restrict__ coords)
{
    const int b = blockIdx.x, j = threadIdx.x;
    if (j >= 33) return;
    float mg = -1e30f;
    for (int sl = 0; sl < 16; ++sl)
        mg = fmaxf(mg, ss[(long)(b * 16 + sl) * 132 + j]);
    float S = 0.f, SX = 0.f, SY = 0.f;
    for (int sl = 0; sl < 16; ++sl) {
        const long o = (long)(b * 16 + sl) * 132;
        float sc = expf((ss[o + j] - mg) * 10.0f);
        S  += ss[o + 33 + j] * sc;
        SX += ss[o + 66 + j] * sc;
        SY += ss[o + 99 + j] * sc;
    }
    coords[2 * (b * 33 + j)]     = SX / S;
    coords[2 * (b * 33 + j) + 1] = SY / S;
}

// ================= bilinear sample (bf16 NHWC feat) + proj =================
__global__ __launch_bounds__(64)
void joint_bf_k(const __hip_bfloat16* __restrict__ fm, const float* __restrict__ coords,
                const float* __restrict__ pw, const float* __restrict__ pb,
                float* __restrict__ jf)
{
    __shared__ float sj[64];
    const int bj = blockIdx.x, b = bj / 33;
    const int tid = threadIdx.x;
    float ix = coords[2 * bj], iy = coords[2 * bj + 1];
    float x0f = fminf(fmaxf(floorf(ix), 0.0f), 255.0f);
    float y0f = fminf(fmaxf(floorf(iy), 0.0f), 255.0f);
    float wx = ix - x0f, wy = iy - y0f;
    int x0 = (int)x0f, y0 = (int)y0f;
    int x1 = min(x0 + 1, 255), y1 = min(y0 + 1, 255);
    const __hip_bfloat16* base = fm + (long)b * 65536 * 64 + tid;
    float v00 = __bfloat162float(base[((long)y0 * 256 + x0) * 64]);
    float v01 = __bfloat162float(base[((long)y0 * 256 + x1) * 64]);
    float v10 = __bfloat162float(base[((long)y1 * 256 + x0) * 64]);
    float v11 = __bfloat162float(base[((long)y1 * 256 + x1) * 64]);
    sj[tid] = v00 * (1 - wx) * (1 - wy) + v01 * wx * (1 - wy)
            + v10 * (1 - wx) * wy + v11 * wx * wy;
    __syncthreads();
    float a = pb[tid];
    for (int k = 0; k < 64; ++k) a = fmaf(sj[k], pw[tid * 64 + k], a);
    jf[(long)bj * 64 + tid] = a;
}

// ================= graph message + GRU =================
__device__ const int d_nbr[33][4] = {
    {0,0,0,0},{1,0,0,0},{2,0,0,0},{3,0,0,0},{4,0,0,0},{5,0,0,0},{6,0,0,0},{7,0,0,0},
    {8,0,0,0},{9,0,0,0},{10,0,0,0},
    {11,12,23,13},{12,11,24,14},{13,11,15,0},{14,12,16,0},{15,13,0,0},{16,14,0,0},
    {17,0,0,0},{18,0,0,0},{19,0,0,0},{20,0,0,0},{21,0,0,0},{22,0,0,0},
    {23,11,24,25},{24,12,23,26},{25,23,27,0},{26,24,28,0},{27,25,0,0},{28,26,0,0},
    {29,0,0,0},{30,0,0,0},{31,0,0,0},{32,0,0,0}};
__device__ const int d_cnt[33] = {1,1,1,1,1,1,1,1,1,1,1,4,4,3,3,2,2,1,1,1,1,1,1,4,4,3,3,2,2,1,1,1,1};

__global__ __launch_bounds__(192)
void gru_k(const float* __restrict__ jf, const float* __restrict__ mw, const float* __restrict__ mb,
           const float* __restrict__ wih, const float* __restrict__ whh,
           const float* __restrict__ bih, const float* __restrict__ bhh,
           float* __restrict__ rbias)
{
    __shared__ float s_mjf[64], s_jf[64], s_msg[64], s_gi[192], s_gh[192], s_ref[64];
    const int bj = blockIdx.x;
    const int b = bj / 33, j = bj % 33;
    const int tid = threadIdx.x;
    if (tid < 64) {
        int cnt = d_cnt[j];
        float s = 0.0f;
        for (int n = 0; n < 4; ++n)
            if (n < cnt) s += jf[((long)b * 33 + d_nbr[j][n]) * 64 + tid];
        s_mjf[tid] = s / (float)cnt;
        s_jf[tid] = jf[(long)bj * 64 + tid];
    }
    __syncthreads();
    if (tid < 64) {
        float a = mb[tid];
        for (int k = 0; k < 64; ++k) a = fmaf(mw[tid * 64 + k], s_mjf[k], a);
        s_msg[tid] = a;
    }
    __syncthreads();
    {
        float a = bih[tid], c = bhh[tid];
        for (int k = 0; k < 64; ++k) {
            a = fmaf(wih[tid * 64 + k], s_msg[k], a);
            c = fmaf(whh[tid * 64 + k], s_jf[k], c);
        }
        s_gi[tid] = a; s_gh[tid] = c;
    }
    __syncthreads();
    if (tid < 64) {
        float r = sigf(s_gi[tid] + s_gh[tid]);
        float z = sigf(s_gi[64 + tid] + s_gh[64 + tid]);
        float n = tanhf(s_gi[128 + tid] + r * s_gh[128 + tid]);
        s_ref[tid] = (1.0f - z) * n + z * s_jf[tid];
    }
    __syncthreads();
    if (tid == 0) {
        float s = 0.0f;
        for (int k = 0; k < 64; ++k) s += s_ref[k];
        rbias[bj] = s * (1.0f / 64.0f);
    }
}

// ================= vis branch =================
__global__ __launch_bounds__(256)
void vispool_bf_k(const __hip_bfloat16* __restrict__ enc, float* __restrict__ p)
{
    int idx = blockIdx.x * 256 + threadIdx.x;  // 65536
    int v = idx & 3, uu = (idx >> 2) & 3, c = (idx >> 4) & 255, b = idx >> 12;
    const __hip_bfloat16* base = enc + (long)b * 64 * 64 * 256 + c;
    float s = 0.0f;
    for (int a = 0; a < 16; ++a)
#pragma unroll
        for (int d = 0; d < 16; ++d)
            s += __bfloat162float(base[((long)(uu * 16 + a) * 64 + (v * 16 + d)) * 256]);
    p[idx] = s * (1.0f / 256.0f);
}

__global__ __launch_bounds__(256)
void visfc1_k(const float* __restrict__ p, const float* __restrict__ w1,
              const float* __restrict__ b1, float* __restrict__ v1)
{
    __shared__ float s_p[4096];
    const int b = blockIdx.x, tid = threadIdx.x;
    for (int i = tid; i < 4096; i += 256) s_p[i] = p[b * 4096 + i];
    __syncthreads();
    float a = b1[tid];
    const float* wr = w1 + (long)tid * 4096;
    for (int k = 0; k < 4096; ++k) a = fmaf(wr[k], s_p[k], a);
    v1[b * 256 + tid] = fmaxf(a, 0.0f);
}

__global__ __launch_bounds__(64)
void visfc2_k(const float* __restrict__ v1, const float* __restrict__ w2,
              const float* __restrict__ b2, float* __restrict__ out)
{
    const int b = blockIdx.x, t = threadIdx.x;
    if (t < 33) {
        float a = b2[t];
        for (int k = 0; k < 256; ++k) a = fmaf(w2[t * 256 + k], v1[b * 256 + k], a);
        out[b * 33 + t] = sigf(a);
    }
}

extern "C" void kernel_launch(void* const* d_in, const int* in_sizes, int n_in,
                              void* d_out, int out_size, void* d_ws, size_t ws_size,
                              hipStream_t stream)
{
    const float* x   = (const float*)d_in[0];
    const float* c1w = (const float*)d_in[1];  const float* c1b = (const float*)d_in[2];
    const float* b1g = (const float*)d_in[3];  const float* b1b = (const float*)d_in[4];
    const float* c2w = (const float*)d_in[5];  const float* c2b = (const float*)d_in[6];
    const float* b2g = (const float*)d_in[7];  const float* b2b = (const float*)d_in[8];
    const float* c3w = (const float*)d_in[9];  const float* c3b = (const float*)d_in[10];
    const float* b3g = (const float*)d_in[11]; const float* b3b = (const float*)d_in[12];
    const float* c4w = (const float*)d_in[13]; const float* c4b = (const float*)d_in[14];
    const float* b4g = (const float*)d_in[15]; const float* b4b = (const float*)d_in[16];
    const float* d1w = (const float*)d_in[17]; const float* d1b = (const float*)d_in[18];
    const float* d2w = (const float*)d_in[19]; const float* d2b = (const float*)d_in[20];
    const float* hw  = (const float*)d_in[21]; const float* hb  = (const float*)d_in[22];
    const float* pw  = (const float*)d_in[23]; const float* pb  = (const float*)d_in[24];
    const float* mw  = (const float*)d_in[25]; const float* mb  = (const float*)d_in[26];
    const float* wih = (const float*)d_in[27]; const float* whh = (const float*)d_in[28];
    const float* bih = (const float*)d_in[29]; const float* bhh = (const float*)d_in[30];
    const float* rw  = (const float*)d_in[31]; const float* rb  = (const float*)d_in[32];
    const float* v1w = (const float*)d_in[33]; const float* v1b = (const float*)d_in[34];
    const float* v2w = (const float*)d_in[35]; const float* v2b = (const float*)d_in[36];

    // ---- lifetime-packed workspace ----
    char* ws = (char*)d_ws;
    __hip_bfloat16* ENC  = (__hip_bfloat16*)(ws + 0L);
    __hip_bfloat16* R1   = (__hip_bfloat16*)(ws + 33554432L);      // H1 -> P1 -> FEAT
    __hip_bfloat16* R2   = (__hip_bfloat16*)(ws + 167772160L);     // H3 -> F -> HEADB
    char*           R3c  = ws + 304095232L;                        // P2
    char* SM = ws + 442507264L;

    __hip_bfloat16* H1B = R1;                 __hip_bfloat16* H1I = R1 + 8288;
    __hip_bfloat16* P1B = R1;                 __hip_bfloat16* P1I = R1 + 8384;
    __hip_bfloat16* FEAT = R1;
    __hip_bfloat16* H3  = R2;
    __hip_bfloat16* F   = R2;
    __hip_bfloat16* HDB = R2;                 __hip_bfloat16* HDI = R2 + 16576;
    __hip_bfloat16* P2B = (__hip_bfloat16*)R3c; __hip_bfloat16* P2I = P2B + 8576;

    __hip_bfloat16* W2B = (__hip_bfloat16*)(SM + 0);
    __hip_bfloat16* W3B = (__hip_bfloat16*)(SM + 36864);
    __hip_bfloat16* W4B = (__hip_bfloat16*)(SM + 184320);
    __hip_bfloat16* WRB = (__hip_bfloat16*)(SM + 774144);
    __hip_bfloat16* WHB = (__hip_bfloat16*)(SM + 847872);
    __hip_bfloat16* WD1 = (__hip_bfloat16*)(SM + 856064);
    __hip_bfloat16* WD2 = (__hip_bfloat16*)(SM + 1118208);
    float* CO = (float*)(SM + 1183744);
    float* JF = (float*)(SM + 1187968);
    float* RB = (float*)(SM + 1323136);
    float* P  = (float*)(SM + 1325248);
    float* V1 = (float*)(SM + 1587392);
    float* SS = (float*)(SM + 1603840);   // 256 x 4 x 33 f32 = 135168 B

    float* out_hm  = (float*)d_out;        // (16,33,256,256)
    float* out_vis = out_hm + 34603008L;   // (16,33)
    __hip_bfloat16* H2 = (__hip_bfloat16*)d_out;  // scratch: conv2 out, dead before refine

    // ---- weight repacks ----
    repack_conv_w_ilv_k<<<(9*64*32 + 255)/256, 256, 0, stream>>>(c2w, W2B, 9, 64, 32, 64, 32);
    repack_conv_w_ilv_k<<<(9*128*64 + 255)/256, 256, 0, stream>>>(c3w, W3B, 9, 128, 64, 128, 64);
    repack_conv_w_ilv_k<<<(9*256*128 + 255)/256, 256, 0, stream>>>(c4w, W4B, 9, 256, 128, 256, 128);
    repack_conv_w_k<<<(9*64*64 + 255)/256, 256, 0, stream>>>(rw, WRB, 9, 33, 33, 64, 64);
    repack_conv_w_ilv_k<<<(1*64*64 + 255)/256, 256, 0, stream>>>(hw, WHB, 1, 33, 64, 64, 64);
    repack_deconv_w_ilv_k<<<(4*128*256 + 255)/256, 256, 0, stream>>>(d1w, WD1, 128, 256);
    repack_deconv_w_ilv_k<<<(4*64*128 + 255)/256, 256, 0, stream>>>(d2w, WD2, 64, 128);

    // halo zeroing
    zero_halo_k<<<(526336 + 255)/256, 256, 0, stream>>>(H1B, 256, 256, 32, 16);
    zero_halo_k<<<(532480 + 255)/256, 256, 0, stream>>>(P2B, 64, 64, 128, 16);

    // 1) conv1 3->32 @256 -> H1 (padded)
    conv1_k<<<dim3(4, 16, 64), 256, 0, stream>>>(x, c1w, c1b, b1g, b1b, H1I);
    // 2) conv2 32->64 @256 -> H2 (d_out scratch)
    mfma_conv_k<2><<<dim3(512, 1, 16), 256, 0, stream>>>(
        H1I, W2B, c2b, b2g, b2b, H2,
        256, 256, 32, 258, 2130048L, 4194304L, 256, 64, 1, 8);
    // 3) pool -> P1 (padded)
    zero_halo_k<<<(528384 + 255)/256, 256, 0, stream>>>(P1B, 128, 128, 64, 16);
    maxpool_bf_k<<<8192, 256, 0, stream>>>(H2, P1I, 128, 128, 64, 2097152L, 130, 1081600L);
    // 4) conv3 64->128 @128 -> H3
    mfma_conv_k<2><<<dim3(128, 1, 32), 256, 0, stream>>>(
        P1I, W3B, c3b, b3g, b3b, H3,
        128, 128, 64, 130, 1081600L, 2097152L, 128, 128, 2, 4);
    // 5) pool -> P2 (padded)
    maxpool_bf_k<<<4096, 256, 0, stream>>>(H3, P2I, 64, 64, 128, 1048576L, 66, 557568L);
    // 6) conv4 128->256 @64 -> ENC
    mfma_conv_k<2><<<dim3(32, 1, 64), 256, 0, stream>>>(
        P2I, W4B, c4b, b4g, b4b, ENC,
        64, 64, 128, 66, 557568L, 1048576L, 64, 256, 4, 2);
    // 7) dc1 256->128 (64->128 up) -> F
    mfma_deconv_k<<<dim3(32, 1, 32), 256, 0, stream>>>(
        ENC, WD1, d1b, F, 64, 64, 256, 128, 2, 2);
    // 8) dc2 128->64 (128->256 up) -> FEAT
    mfma_deconv_k<<<dim3(128, 1, 16), 256, 0, stream>>>(
        F, WD2, d2b, FEAT, 128, 128, 128, 64, 1, 4);
    // 9) head 1x1 + sigmoid -> HDI (padded bf16 NHWC)
    zero_halo_k<<<(1052672 + 255)/256, 256, 0, stream>>>(HDB, 256, 256, 64, 16);
    mfma_head_k<<<dim3(512, 1, 16), 256, 0, stream>>>(FEAT, WHB, hb, HDI);
    // 10) hierarchical soft-argmax (slabs + combine)
    softargmax_slab_k<<<256, 256, 0, stream>>>(HDI, SS);
    softargmax_comb_k<<<16, 64, 0, stream>>>(SS, CO);
    // 11) bilinear + proj
    joint_bf_k<<<528, 64, 0, stream>>>(FEAT, CO, pw, pb, JF);
    // 12) message + GRU -> refined_bias
    gru_k<<<528, 192, 0, stream>>>(JF, mw, mb, wih, whh, bih, bhh, RB);
    // 13) refine 33->33 @256 + bias + sigmoid -> out_hm (f32 nchw, cooperative stores)
    mfma_refine_k<<<dim3(512, 1, 16), 256, 26880, stream>>>(
        HDI, WRB, rb, RB, out_hm);
    // 14) vis pool -> P (16,4096)
    vispool_bf_k<<<256, 256, 0, stream>>>(ENC, P);
    // 15) fc1 + relu
    visfc1_k<<<16, 256, 0, stream>>>(P, v1w, v1b, V1);
    // 16) fc2 + sigmoid
    visfc2_k<<<16, 64, 0, stream>>>(V1, v2w, v2b, out_vis);
}

// Round 20
// 1579.375 us; speedup vs baseline: 1.1750x; 1.0273x over previous
//
#include <hip/hip_runtime.h>
#include <hip/hip_bf16.h>
#include <math.h>

#define BN_RS 0.99999500003749977f  // 1/sqrt(1 + 1e-5)

typedef __attribute__((ext_vector_type(8))) __bf16 bf16x8;
typedef __attribute__((ext_vector_type(4))) float f32x4;

union U16 { uint4 u; bf16x8 v; __hip_bfloat16 h[8]; };
union U8  { uint2 u; __hip_bfloat16 h[4]; };

__device__ __forceinline__ float sigf(float v) { return 1.0f / (1.0f + expf(-v)); }

// ================= weight repack =================
__global__ __launch_bounds__(256)
void repack_conv_w_k(const float* __restrict__ w, __hip_bfloat16* __restrict__ wb,
                     int taps, int Co, int Ci, int CoT, int Kp)
{
    int i = blockIdx.x * 256 + threadIdx.x;
    int tot = taps * CoT * Kp;
    if (i >= tot) return;
    int k = i % Kp, n = (i / Kp) % CoT, t = i / (Kp * CoT);
    float v = (n < Co && k < Ci) ? w[((long)n * Ci + k) * taps + t] : 0.0f;
    wb[i] = __float2bfloat16(v);
}
__global__ __launch_bounds__(256)
void repack_conv_w_ilv_k(const float* __restrict__ w, __hip_bfloat16* __restrict__ wb,
                         int taps, int Co, int Ci, int CoT, int Kp)
{
    int i = blockIdx.x * 256 + threadIdx.x;
    int tot = taps * CoT * Kp;
    if (i >= tot) return;
    int k = i % Kp, n = (i / Kp) % CoT, t = i / (Kp * CoT);
    int grp = n >> 6, r = n & 63;
    int c = (grp << 6) + (r & 15) * 4 + (r >> 4);
    float v = (c < Co && k < Ci) ? w[((long)c * Ci + k) * taps + t] : 0.0f;
    wb[i] = __float2bfloat16(v);
}
__global__ __launch_bounds__(256)
void repack_deconv_w_ilv_k(const float* __restrict__ w, __hip_bfloat16* __restrict__ wb,
                           int Co, int Ci)
{
    int i = blockIdx.x * 256 + threadIdx.x;
    int tot = 4 * Co * Ci;
    if (i >= tot) return;
    int k = i % Ci, n = (i / Ci) % Co, q = i / (Ci * Co);
    int grp = n >> 6, r = n & 63;
    int c = (grp << 6) + (r & 15) * 4 + (r >> 4);
    wb[i] = __float2bfloat16(w[((long)k * Co + c) * 4 + q]);
}

// ================= zero the 1-px halo of a padded NHWC buffer =================
__global__ __launch_bounds__(256)
void zero_halo_k(__hip_bfloat16* __restrict__ buf, int H, int W, int C, int B)
{
    const int P = W + 2;
    const long per = (long)(2 * P + 2 * H) * C;
    long idx = (long)blockIdx.x * 256 + threadIdx.x;
    if (idx >= per * B) return;
    int b = (int)(idx / per);
    long r = idx % per;
    long off;
    if (r < (long)2 * P * C) {
        int row = (r >= (long)P * C) ? (H + 1) : 0;
        long r2 = r % ((long)P * C);
        off = (((long)b * (H + 2) + row) * P) * C + r2;
    } else {
        long r2 = r - (long)2 * P * C;
        int row = 1 + (int)(r2 / (2 * C));
        int side = (int)((r2 / C) & 1);
        int ch = (int)(r2 % C);
        off = (((long)b * (H + 2) + row) * P + (side ? (W + 1) : 0)) * C + ch;
    }
    buf[off] = __float2bfloat16(0.0f);
}

// ================= conv1 (3->32, scalar fp32, writes bf16 NHWC padded-interior) =================
__global__ __launch_bounds__(256)
void conv1_k(const float* __restrict__ x, const float* __restrict__ w,
             const float* __restrict__ cb, const float* __restrict__ g,
             const float* __restrict__ bb, __hip_bfloat16* __restrict__ out)
{
    __shared__ float sw[216];
    const int tid = threadIdx.x;
    const int b = blockIdx.z >> 2, cg = blockIdx.z & 3, co0 = cg * 8;
    for (int i = tid; i < 216; i += 256) {
        int t = i % 9, co = (i / 9) % 8, ci = i / 72;
        sw[i] = w[((co0 + co) * 3 + ci) * 9 + t];
    }
    __syncthreads();
    const int tx = tid & 15, ty = tid >> 4;
    const int y = blockIdx.y * 16 + ty;
    const int xs = blockIdx.x * 64 + tx;
    float acc[4][8];
#pragma unroll
    for (int p = 0; p < 4; ++p)
#pragma unroll
        for (int c = 0; c < 8; ++c) acc[p][c] = 0.0f;
    for (int ci = 0; ci < 3; ++ci) {
        const float* plane = x + ((long)b * 3 + ci) * 65536;
#pragma unroll
        for (int t = 0; t < 9; ++t) {
            const int dy = t / 3 - 1, dx = t % 3 - 1;
            const int yy = y + dy;
            if ((unsigned)yy < 256u) {
                const float* row = plane + yy * 256;
                float wsr[8];
#pragma unroll
                for (int c = 0; c < 8; ++c) wsr[c] = sw[ci * 72 + c * 9 + t];
#pragma unroll
                for (int p = 0; p < 4; ++p) {
                    const int xx = xs + p * 16 + dx;
                    const float v = ((unsigned)xx < 256u) ? row[xx] : 0.0f;
#pragma unroll
                    for (int c = 0; c < 8; ++c) acc[p][c] = fmaf(v, wsr[c], acc[p][c]);
                }
            }
        }
    }
#pragma unroll
    for (int p = 0; p < 4; ++p) {
        U16 o;
#pragma unroll
        for (int c = 0; c < 8; ++c) {
            const int cc = co0 + c;
            float v = fmaxf(acc[p][c] + cb[cc], 0.0f) * (g[cc] * BN_RS) + bb[cc];
            o.h[c] = __float2bfloat16(v);
        }
        *(uint4*)(void*)(out + ((long)b * 2130048L + ((long)y * 258 + xs + p * 16) * 32) + co0) = o.u;
    }
}

// ================= MFMA conv 3x3 (implicit GEMM, software-pipelined phases) =================
template<int MI>
__global__ __launch_bounds__(256)
void mfma_conv_k(const __hip_bfloat16* __restrict__ in,
                 const __hip_bfloat16* __restrict__ wb,
                 const float* __restrict__ cbias,
                 const float* __restrict__ bng, const float* __restrict__ bnb,
                 __hip_bfloat16* __restrict__ out_bf,
                 int H, int W, int Cin, int PIT, long bstride, long obstride, int OPIT,
                 int CoutT, int CG, int S)
{
    const int tid = threadIdx.x;
    const int wid = tid >> 6, lane = tid & 63;
    const int ln = lane & 15, kg = lane >> 4;
    const int nx = gridDim.x;
    const int bx = (blockIdx.x & 7) * (nx >> 3) + (blockIdx.x >> 3);
    const int u = bx * 4 + wid;
    const int y = u / S, x0 = (u % S) * (MI * 16);
    const int b = blockIdx.z / CG, cg = blockIdx.z % CG;
    const int co0 = cg * 64;
    const int KC = Cin >> 5;
    const int NPH = KC * 9;

    f32x4 acc[MI][4];
#pragma unroll
    for (int i = 0; i < MI; ++i)
#pragma unroll
        for (int j = 0; j < 4; ++j) acc[i][j] = f32x4{0.f, 0.f, 0.f, 0.f};

    bf16x8 wfA[4]; U16 avA[MI];
    bf16x8 wfB[4]; U16 avB[MI];

    auto LD = [&](int ph, bf16x8 (&wf)[4], U16 (&av)[MI]) {
        const int kc = ph / 9, t = ph - kc * 9;
        const int kofs = kc * 32 + kg * 8;
        const int dy = t / 3 - 1, dx = t - (t / 3) * 3 - 1;
#pragma unroll
        for (int ni = 0; ni < 4; ++ni)
            wf[ni] = *(const bf16x8*)(const void*)(wb + ((long)t * CoutT + co0 + ni * 16 + ln) * Cin + kofs);
        const long rowb = (long)b * bstride + (long)(y + dy) * PIT * Cin + kofs;
#pragma unroll
        for (int mi = 0; mi < MI; ++mi)
            av[mi].u = *(const uint4*)(const void*)(in + rowb + (long)(x0 + mi * 16 + ln + dx) * Cin);
    };
    auto MM = [&](bf16x8 (&wf)[4], U16 (&av)[MI]) {
#pragma unroll
        for (int mi = 0; mi < MI; ++mi)
#pragma unroll
            for (int ni = 0; ni < 4; ++ni)
                acc[mi][ni] = __builtin_amdgcn_mfma_f32_16x16x32_bf16(av[mi].v, wf[ni], acc[mi][ni], 0, 0, 0);
    };

    LD(0, wfA, avA);
    int ph = 0;
    for (; ph + 1 < NPH; ph += 2) {
        LD(ph + 1, wfB, avB);
        MM(wfA, avA);
        if (ph + 2 < NPH) LD(ph + 2, wfA, avA);
        MM(wfB, avB);
    }
    if (ph < NPH) MM(wfA, avA);

#pragma unroll
    for (int mi = 0; mi < MI; ++mi) {
#pragma unroll
        for (int r = 0; r < 4; ++r) {
            const int px = x0 + mi * 16 + kg * 4 + r;
            const long pb = (long)b * obstride + ((long)y * OPIT + px) * CoutT + co0;
            U8 o;
#pragma unroll
            for (int ni = 0; ni < 4; ++ni) {
                const int c = co0 + ln * 4 + ni;
                float v = acc[mi][ni][r] + cbias[c];
                v = fmaxf(v, 0.0f) * (bng[c] * BN_RS) + bnb[c];
                o.h[ni] = __float2bfloat16(v);
            }
            *(uint2*)(void*)(out_bf + pb + ln * 4) = o.u;
        }
    }
}

// ================= MFMA deconv 2x2 + ReLU (interleaved weights, packed stores) =========
__global__ __launch_bounds__(256)
void mfma_deconv_k(const __hip_bfloat16* __restrict__ in,
                   const __hip_bfloat16* __restrict__ wb,
                   const float* __restrict__ bias,
                   __hip_bfloat16* __restrict__ out,
                   int H, int W, int Cin, int CoutT, int CG, int S)
{
    const int tid = threadIdx.x;
    const int wid = tid >> 6, lane = tid & 63;
    const int ln = lane & 15, kg = lane >> 4;
    const int nx = gridDim.x;
    const int bx = (blockIdx.x & 7) * (nx >> 3) + (blockIdx.x >> 3);
    const int u = bx * 4 + wid;
    const int y = u / S, x0 = (u % S) * 32;
    const int b = blockIdx.z / CG, cg = blockIdx.z % CG;
    const int co0 = cg * 64;
    const int KC = Cin >> 5;
    const long inb = (long)b * H * W * Cin;
    const int W2 = W * 2;
    const long ob = (long)b * 4 * H * W * CoutT;

    for (int q = 0; q < 4; ++q) {
        const int dy = q >> 1, dx = q & 1;
        f32x4 acc[2][4];
#pragma unroll
        for (int i = 0; i < 2; ++i)
#pragma unroll
            for (int j = 0; j < 4; ++j) acc[i][j] = f32x4{0.f, 0.f, 0.f, 0.f};
        for (int kc = 0; kc < KC; ++kc) {
            const int kofs = kc * 32 + kg * 8;
            bf16x8 wfr[4];
            U16 av[2];
#pragma unroll
            for (int ni = 0; ni < 4; ++ni)
                wfr[ni] = *(const bf16x8*)(const void*)(wb + ((long)q * CoutT + co0 + ni * 16 + ln) * Cin + kofs);
#pragma unroll
            for (int mi = 0; mi < 2; ++mi)
                av[mi].u = *(const uint4*)(const void*)(in + inb + ((long)y * W + x0 + mi * 16 + ln) * Cin + kofs);
#pragma unroll
            for (int mi = 0; mi < 2; ++mi)
#pragma unroll
                for (int ni = 0; ni < 4; ++ni)
                    acc[mi][ni] = __builtin_amdgcn_mfma_f32_16x16x32_bf16(av[mi].v, wfr[ni], acc[mi][ni], 0, 0, 0);
        }
#pragma unroll
        for (int mi = 0; mi < 2; ++mi) {
#pragma unroll
            for (int r = 0; r < 4; ++r) {
                const int xl = x0 + mi * 16 + kg * 4 + r;
                const long pb = ob + ((long)(2 * y + dy) * W2 + 2 * xl + dx) * CoutT + co0;
                U8 o;
#pragma unroll
                for (int ni = 0; ni < 4; ++ni) {
                    const int c = co0 + ln * 4 + ni;
                    float v = fmaxf(acc[mi][ni][r] + bias[c], 0.0f);
                    o.h[ni] = __float2bfloat16(v);
                }
                *(uint2*)(void*)(out + pb + ln * 4) = o.u;
            }
        }
    }
}

// ================= head: 1x1 conv 64->33(pad64) + sigmoid -> bf16 NHWC padded ==========
__global__ __launch_bounds__(256)
void mfma_head_k(const __hip_bfloat16* __restrict__ in,
                 const __hip_bfloat16* __restrict__ wb,
                 const float* __restrict__ hb,
                 __hip_bfloat16* __restrict__ out)
{
    const int tid = threadIdx.x;
    const int wid = tid >> 6, lane = tid & 63;
    const int ln = lane & 15, kg = lane >> 4;
    const int nx = gridDim.x;
    const int bx = (blockIdx.x & 7) * (nx >> 3) + (blockIdx.x >> 3);
    const int u = bx * 4 + wid;
    const int y = u >> 3, x0 = (u & 7) * 32;
    const int b = blockIdx.z;

    f32x4 acc[2][4];
#pragma unroll
    for (int i = 0; i < 2; ++i)
#pragma unroll
        for (int j = 0; j < 4; ++j) acc[i][j] = f32x4{0.f, 0.f, 0.f, 0.f};

    bf16x8 wfA[4], wfB[4];
    U16 avA[2], avB[2];
    {
        const int kofs0 = kg * 8, kofs1 = 32 + kg * 8;
#pragma unroll
        for (int ni = 0; ni < 4; ++ni) {
            wfA[ni] = *(const bf16x8*)(const void*)(wb + ((long)(ni * 16 + ln)) * 64 + kofs0);
            wfB[ni] = *(const bf16x8*)(const void*)(wb + ((long)(ni * 16 + ln)) * 64 + kofs1);
        }
        const long rb = (long)b * 4194304L;
#pragma unroll
        for (int mi = 0; mi < 2; ++mi) {
            const long px = ((long)y * 256 + x0 + mi * 16 + ln) * 64;
            avA[mi].u = *(const uint4*)(const void*)(in + rb + px + kofs0);
            avB[mi].u = *(const uint4*)(const void*)(in + rb + px + kofs1);
        }
    }
#pragma unroll
    for (int mi = 0; mi < 2; ++mi)
#pragma unroll
        for (int ni = 0; ni < 4; ++ni)
            acc[mi][ni] = __builtin_amdgcn_mfma_f32_16x16x32_bf16(avA[mi].v, wfA[ni], acc[mi][ni], 0, 0, 0);
#pragma unroll
    for (int mi = 0; mi < 2; ++mi)
#pragma unroll
        for (int ni = 0; ni < 4; ++ni)
            acc[mi][ni] = __builtin_amdgcn_mfma_f32_16x16x32_bf16(avB[mi].v, wfB[ni], acc[mi][ni], 0, 0, 0);

#pragma unroll
    for (int mi = 0; mi < 2; ++mi) {
#pragma unroll
        for (int r = 0; r < 4; ++r) {
            const int px = x0 + mi * 16 + kg * 4 + r;
            const long pb = (long)b * 4260096L + ((long)y * 258 + px) * 64;
            U8 o;
#pragma unroll
            for (int ni = 0; ni < 4; ++ni) {
                const int c = ln * 4 + ni;
                float v = (c < 33) ? sigf(acc[mi][ni][r] + hb[c]) : 0.0f;
                o.h[ni] = __float2bfloat16(v);
            }
            *(uint2*)(void*)(out + pb + ln * 4) = o.u;
        }
    }
}

// ================= refine: 3x3 conv 33(pad64)->33 + bias + rbias + sigmoid -> f32 NCHW =
__global__ __launch_bounds__(256)
void mfma_refine_k(const __hip_bfloat16* __restrict__ in,   // HDI padded interior
                   const __hip_bfloat16* __restrict__ wb,   // [9][64][64] plain
                   const float* __restrict__ cbias, const float* __restrict__ ebias,
                   float* __restrict__ out_f32)
{
    extern __shared__ float ltr[];  // 4 waves x 48ch x 35 f32
    const int tid = threadIdx.x;
    const int wid = tid >> 6, lane = tid & 63;
    const int ln = lane & 15, kg = lane >> 4;
    const int nx = gridDim.x;
    const int bx = (blockIdx.x & 7) * (nx >> 3) + (blockIdx.x >> 3);
    const int u = bx * 4 + wid;
    const int y = u >> 3, x0 = (u & 7) * 32;
    const int b = blockIdx.z;

    f32x4 acc[2][3];
#pragma unroll
    for (int i = 0; i < 2; ++i)
#pragma unroll
        for (int j = 0; j < 3; ++j) acc[i][j] = f32x4{0.f, 0.f, 0.f, 0.f};

    bf16x8 wfA[3], wfB[3];
    U16 avA[2], avB[2];

    auto LD = [&](int ph, bf16x8 (&wf)[3], U16 (&av)[2]) {
        const int kc = (ph >= 9) ? 1 : 0;
        const int t = ph - kc * 9;
        const int kofs = kc * 32 + kg * 8;
        const int dy = t / 3 - 1, dx = t - (t / 3) * 3 - 1;
#pragma unroll
        for (int ni = 0; ni < 3; ++ni)
            wf[ni] = *(const bf16x8*)(const void*)(wb + ((long)t * 64 + ni * 16 + ln) * 64 + kofs);
        const long rowb = (long)b * 4260096L + (long)(y + dy) * 258 * 64 + kofs;
#pragma unroll
        for (int mi = 0; mi < 2; ++mi)
            av[mi].u = *(const uint4*)(const void*)(in + rowb + (long)(x0 + mi * 16 + ln + dx) * 64);
    };
    auto MM = [&](bf16x8 (&wf)[3], U16 (&av)[2]) {
#pragma unroll
        for (int mi = 0; mi < 2; ++mi)
#pragma unroll
            for (int ni = 0; ni < 3; ++ni)
                acc[mi][ni] = __builtin_amdgcn_mfma_f32_16x16x32_bf16(av[mi].v, wf[ni], acc[mi][ni], 0, 0, 0);
    };

    LD(0, wfA, avA);
    for (int ph = 0; ph < 18; ph += 2) {
        LD(ph + 1, wfB, avB);
        MM(wfA, avA);
        if (ph + 2 < 18) LD(ph + 2, wfA, avA);
        MM(wfB, avB);
    }

    float* wt = ltr + wid * 1680;  // 48*35
#pragma unroll
    for (int mi = 0; mi < 2; ++mi) {
#pragma unroll
        for (int r = 0; r < 4; ++r) {
            const int pxl = mi * 16 + kg * 4 + r;
#pragma unroll
            for (int ni = 0; ni < 3; ++ni) {
                const int c = ni * 16 + ln;
                float eb = (c < 33) ? (cbias[c] + ebias[b * 33 + c]) : 0.0f;
                wt[c * 35 + pxl] = sigf(acc[mi][ni][r] + eb);
            }
        }
    }
    __syncthreads();
    const int yb = (bx * 4) >> 3;
    const int xb = ((bx * 4) & 7) * 32;
    const int coff = bx % 33;
    for (int i = tid; i < 4224; i += 256) {   // 33ch x 128px
        int cl = i >> 7, p = i & 127;
        int c = cl + coff; if (c >= 33) c -= 33;
        float v = ltr[(p >> 5) * 1680 + c * 35 + (p & 31)];
        out_f32[((long)b * 33 + c) * 65536L + (long)yb * 256 + xb + p] = v;
    }
}

// ================= maxpool 2x2 on bf16 NHWC (padded-interior output) =================
__global__ __launch_bounds__(256)
void maxpool_bf_k(const __hip_bfloat16* __restrict__ in, __hip_bfloat16* __restrict__ out,
                  int Ho, int Wo, int C, long total, int OPIT, long obstride)
{
    long idx = (long)blockIdx.x * 256 + threadIdx.x;
    if (idx >= total) return;
    const int ng = C >> 3;
    const int cg = (int)(idx % ng);
    long pix = idx / ng;
    const int xo = (int)(pix % Wo); pix /= Wo;
    const int yo = (int)(pix % Ho);
    const int b = (int)(pix / Ho);
    const int Wi = Wo * 2;
    const __hip_bfloat16* p = in + (((long)b * 2 * Ho + 2 * yo) * Wi + 2 * xo) * C + cg * 8;
    U16 a0, a1, a2, a3, o;
    a0.u = *(const uint4*)(const void*)p;
    a1.u = *(const uint4*)(const void*)(p + C);
    a2.u = *(const uint4*)(const void*)(p + (long)Wi * C);
    a3.u = *(const uint4*)(const void*)(p + (long)Wi * C + C);
#pragma unroll
    for (int j = 0; j < 8; ++j) {
        float m = fmaxf(fmaxf(__bfloat162float(a0.h[j]), __bfloat162float(a1.h[j])),
                        fmaxf(__bfloat162float(a2.h[j]), __bfloat162float(a3.h[j])));
        o.h[j] = __float2bfloat16(m);
    }
    *(uint4*)(void*)(out + (long)b * obstride + ((long)yo * OPIT + xo) * C + cg * 8) = o.u;
}

// ================= hierarchical soft-argmax over bf16 NHWC padded heatmap =========
__global__ __launch_bounds__(256)
void softargmax_slab_k(const __hip_bfloat16* __restrict__ hd, float* __restrict__ ss)
{
    __shared__ float sm[64 * 33];
    __shared__ float mg[64];
    const int blk = blockIdx.x;
    const int b = blk >> 4, slab = blk & 15;
    const int tid = threadIdx.x;
    const int pxl = tid >> 3, cg = tid & 7;
    const __hip_bfloat16* base = hd + (long)b * 4260096L + (long)(slab * 16) * 258 * 64 + cg * 8;

    float m8[8];
#pragma unroll
    for (int c = 0; c < 8; ++c) m8[c] = -1e30f;
    for (int yy = 0; yy < 16; ++yy)
        for (int xc = 0; xc < 8; ++xc) {
            U16 v; v.u = *(const uint4*)(const void*)(base + ((long)yy * 258 + xc * 32 + pxl) * 64);
#pragma unroll
            for (int c = 0; c < 8; ++c) m8[c] = fmaxf(m8[c], __bfloat162float(v.h[c]));
        }
#pragma unroll
    for (int c = 0; c < 8; ++c) sm[(cg * 8 + c) * 33 + pxl] = m8[c];
    __syncthreads();
    for (int s = 16; s > 0; s >>= 1) {
        if (pxl < s)
#pragma unroll
            for (int c = 0; c < 8; ++c) {
                int a = (cg * 8 + c) * 33;
                sm[a + pxl] = fmaxf(sm[a + pxl], sm[a + pxl + s]);
            }
        __syncthreads();
    }
    if (tid < 64) mg[tid] = sm[tid * 33];
    __syncthreads();
    if (tid < 33) ss[(long)blk * 132 + tid] = mg[tid];
    float mm[8];
#pragma unroll
    for (int c = 0; c < 8; ++c) mm[c] = mg[cg * 8 + c];

    float s8[8], sx8[8], sy8[8];
#pragma unroll
    for (int c = 0; c < 8; ++c) { s8[c] = 0.f; sx8[c] = 0.f; sy8[c] = 0.f; }
    for (int yy = 0; yy < 16; ++yy) {
        const float fy = (float)(slab * 16 + yy);
        for (int xc = 0; xc < 8; ++xc) {
            const int x = xc * 32 + pxl;
            U16 v; v.u = *(const uint4*)(const void*)(base + ((long)yy * 258 + x) * 64);
#pragma unroll
            for (int c = 0; c < 8; ++c) {
                float e = expf((__bfloat162float(v.h[c]) - mm[c]) * 10.0f);
                s8[c] += e; sx8[c] += e * (float)x; sy8[c] += e * fy;
            }
        }
    }
    for (int which = 0; which < 3; ++which) {
        __syncthreads();
#pragma unroll
        for (int c = 0; c < 8; ++c)
            sm[(cg * 8 + c) * 33 + pxl] = (which == 0) ? s8[c] : (which == 1) ? sx8[c] : sy8[c];
        __syncthreads();
        for (int s = 16; s > 0; s >>= 1) {
            if (pxl < s)
#pragma unroll
                for (int c = 0; c < 8; ++c) {
                    int a = (cg * 8 + c) * 33;
                    sm[a + pxl] += sm[a + pxl + s];
                }
            __syncthreads();
        }
        if (tid < 33) ss[(long)blk * 132 + (which + 1) * 33 + tid] = sm[tid * 33];
    }
}

__global__ __launch_bounds__(64)
void softargmax_comb_k(const float* __restrict__ ss, float* __restrict__ coords)
{
    const int b = blockIdx.x, j = threadIdx.x;
    if (j >= 33) return;
    float mg = -1e30f;
    for (int sl = 0; sl < 16; ++sl)
        mg = fmaxf(mg, ss[(long)(b * 16 + sl) * 132 + j]);
    float S = 0.f, SX = 0.f, SY = 0.f;
    for (int sl = 0; sl < 16; ++sl) {
        const long o = (long)(b * 16 + sl) * 132;
        float sc = expf((ss[o + j] - mg) * 10.0f);
        S  += ss[o + 33 + j] * sc;
        SX += ss[o + 66 + j] * sc;
        SY += ss[o + 99 + j] * sc;
    }
    coords[2 * (b * 33 + j)]     = SX / S;
    coords[2 * (b * 33 + j) + 1] = SY / S;
}

// ================= bilinear sample (bf16 NHWC feat) + proj =================
__global__ __launch_bounds__(64)
void joint_bf_k(const __hip_bfloat16* __restrict__ fm, const float* __restrict__ coords,
                const float* __restrict__ pw, const float* __restrict__ pb,
                float* __restrict__ jf)
{
    __shared__ float sj[64];
    const int bj = blockIdx.x, b = bj / 33;
    const int tid = threadIdx.x;
    float ix = coords[2 * bj], iy = coords[2 * bj + 1];
    float x0f = fminf(fmaxf(floorf(ix), 0.0f), 255.0f);
    float y0f = fminf(fmaxf(floorf(iy), 0.0f), 255.0f);
    float wx = ix - x0f, wy = iy - y0f;
    int x0 = (int)x0f, y0 = (int)y0f;
    int x1 = min(x0 + 1, 255), y1 = min(y0 + 1, 255);
    const __hip_bfloat16* base = fm + (long)b * 65536 * 64 + tid;
    float v00 = __bfloat162float(base[((long)y0 * 256 + x0) * 64]);
    float v01 = __bfloat162float(base[((long)y0 * 256 + x1) * 64]);
    float v10 = __bfloat162float(base[((long)y1 * 256 + x0) * 64]);
    float v11 = __bfloat162float(base[((long)y1 * 256 + x1) * 64]);
    sj[tid] = v00 * (1 - wx) * (1 - wy) + v01 * wx * (1 - wy)
            + v10 * (1 - wx) * wy + v11 * wx * wy;
    __syncthreads();
    float a = pb[tid];
    for (int k = 0; k < 64; ++k) a = fmaf(sj[k], pw[tid * 64 + k], a);
    jf[(long)bj * 64 + tid] = a;
}

// ================= graph message + GRU =================
__device__ const int d_nbr[33][4] = {
    {0,0,0,0},{1,0,0,0},{2,0,0,0},{3,0,0,0},{4,0,0,0},{5,0,0,0},{6,0,0,0},{7,0,0,0},
    {8,0,0,0},{9,0,0,0},{10,0,0,0},
    {11,12,23,13},{12,11,24,14},{13,11,15,0},{14,12,16,0},{15,13,0,0},{16,14,0,0},
    {17,0,0,0},{18,0,0,0},{19,0,0,0},{20,0,0,0},{21,0,0,0},{22,0,0,0},
    {23,11,24,25},{24,12,23,26},{25,23,27,0},{26,24,28,0},{27,25,0,0},{28,26,0,0},
    {29,0,0,0},{30,0,0,0},{31,0,0,0},{32,0,0,0}};
__device__ const int d_cnt[33] = {1,1,1,1,1,1,1,1,1,1,1,4,4,3,3,2,2,1,1,1,1,1,1,4,4,3,3,2,2,1,1,1,1};

__global__ __launch_bounds__(192)
void gru_k(const float* __restrict__ jf, const float* __restrict__ mw, const float* __restrict__ mb,
           const float* __restrict__ wih, const float* __restrict__ whh,
           const float* __restrict__ bih, const float* __restrict__ bhh,
           float* __restrict__ rbias)
{
    __shared__ float s_mjf[64], s_jf[64], s_msg[64], s_gi[192], s_gh[192], s_ref[64];
    const int bj = blockIdx.x;
    const int b = bj / 33, j = bj % 33;
    const int tid = threadIdx.x;
    if (tid < 64) {
        int cnt = d_cnt[j];
        float s = 0.0f;
        for (int n = 0; n < 4; ++n)
            if (n < cnt) s += jf[((long)b * 33 + d_nbr[j][n]) * 64 + tid];
        s_mjf[tid] = s / (float)cnt;
        s_jf[tid] = jf[(long)bj * 64 + tid];
    }
    __syncthreads();
    if (tid < 64) {
        float a = mb[tid];
        for (int k = 0; k < 64; ++k) a = fmaf(mw[tid * 64 + k], s_mjf[k], a);
        s_msg[tid] = a;
    }
    __syncthreads();
    {
        float a = bih[tid], c = bhh[tid];
        for (int k = 0; k < 64; ++k) {
            a = fmaf(wih[tid * 64 + k], s_msg[k], a);
            c = fmaf(whh[tid * 64 + k], s_jf[k], c);
        }
        s_gi[tid] = a; s_gh[tid] = c;
    }
    __syncthreads();
    if (tid < 64) {
        float r = sigf(s_gi[tid] + s_gh[tid]);
        float z = sigf(s_gi[64 + tid] + s_gh[64 + tid]);
        float n = tanhf(s_gi[128 + tid] + r * s_gh[128 + tid]);
        s_ref[tid] = (1.0f - z) * n + z * s_jf[tid];
    }
    __syncthreads();
    if (tid == 0) {
        float s = 0.0f;
        for (int k = 0; k < 64; ++k) s += s_ref[k];
        rbias[bj] = s * (1.0f / 64.0f);
    }
}

// ================= vis branch =================
__global__ __launch_bounds__(256)
void vispool_bf_k(const __hip_bfloat16* __restrict__ enc, float* __restrict__ p)
{
    int idx = blockIdx.x * 256 + threadIdx.x;  // 65536
    int v = idx & 3, uu = (idx >> 2) & 3, c = (idx >> 4) & 255, b = idx >> 12;
    const __hip_bfloat16* base = enc + (long)b * 64 * 64 * 256 + c;
    float s = 0.0f;
    for (int a = 0; a < 16; ++a)
#pragma unroll
        for (int d = 0; d < 16; ++d)
            s += __bfloat162float(base[((long)(uu * 16 + a) * 64 + (v * 16 + d)) * 256]);
    p[idx] = s * (1.0f / 256.0f);
}

__global__ __launch_bounds__(256)
void visfc1_k(const float* __restrict__ p, const float* __restrict__ w1,
              const float* __restrict__ b1, float* __restrict__ v1)
{
    __shared__ float s_p[4096];
    const int b = blockIdx.x, tid = threadIdx.x;
    for (int i = tid; i < 4096; i += 256) s_p[i] = p[b * 4096 + i];
    __syncthreads();
    float a = b1[tid];
    const float* wr = w1 + (long)tid * 4096;
    for (int k = 0; k < 4096; ++k) a = fmaf(wr[k], s_p[k], a);
    v1[b * 256 + tid] = fmaxf(a, 0.0f);
}

__global__ __launch_bounds__(64)
void visfc2_k(const float* __restrict__ v1, const float* __restrict__ w2,
              const float* __restrict__ b2, float* __restrict__ out)
{
    const int b = blockIdx.x, t = threadIdx.x;
    if (t < 33) {
        float a = b2[t];
        for (int k = 0; k < 256; ++k) a = fmaf(w2[t * 256 + k], v1[b * 256 + k], a);
        out[b * 33 + t] = sigf(a);
    }
}

extern "C" void kernel_launch(void* const* d_in, const int* in_sizes, int n_in,
                              void* d_out, int out_size, void* d_ws, size_t ws_size,
                              hipStream_t stream)
{
    const float* x   = (const float*)d_in[0];
    const float* c1w = (const float*)d_in[1];  const float* c1b = (const float*)d_in[2];
    const float* b1g = (const float*)d_in[3];  const float* b1b = (const float*)d_in[4];
    const float* c2w = (const float*)d_in[5];  const float* c2b = (const float*)d_in[6];
    const float* b2g = (const float*)d_in[7];  const float* b2b = (const float*)d_in[8];
    const float* c3w = (const float*)d_in[9];  const float* c3b = (const float*)d_in[10];
    const float* b3g = (const float*)d_in[11]; const float* b3b = (const float*)d_in[12];
    const float* c4w = (const float*)d_in[13]; const float* c4b = (const float*)d_in[14];
    const float* b4g = (const float*)d_in[15]; const float* b4b = (const float*)d_in[16];
    const float* d1w = (const float*)d_in[17]; const float* d1b = (const float*)d_in[18];
    const float* d2w = (const float*)d_in[19]; const float* d2b = (const float*)d_in[20];
    const float* hw  = (const float*)d_in[21]; const float* hb  = (const float*)d_in[22];
    const float* pw  = (const float*)d_in[23]; const float* pb  = (const float*)d_in[24];
    const float* mw  = (const float*)d_in[25]; const float* mb  = (const float*)d_in[26];
    const float* wih = (const float*)d_in[27]; const float* whh = (const float*)d_in[28];
    const float* bih = (const float*)d_in[29]; const float* bhh = (const float*)d_in[30];
    const float* rw  = (const float*)d_in[31]; const float* rb  = (const float*)d_in[32];
    const float* v1w = (const float*)d_in[33]; const float* v1b = (const float*)d_in[34];
    const float* v2w = (const float*)d_in[35]; const float* v2b = (const float*)d_in[36];

    // ---- lifetime-packed workspace ----
    char* ws = (char*)d_ws;
    __hip_bfloat16* ENC  = (__hip_bfloat16*)(ws + 0L);
    __hip_bfloat16* R1   = (__hip_bfloat16*)(ws + 33554432L);      // H1 -> P1 -> FEAT
    __hip_bfloat16* R2   = (__hip_bfloat16*)(ws + 167772160L);     // H3 -> F -> HEADB
    char*           R3c  = ws + 304095232L;                        // P2
    char* SM = ws + 442507264L;

    __hip_bfloat16* H1B = R1;                 __hip_bfloat16* H1I = R1 + 8288;
    __hip_bfloat16* P1B = R1;                 __hip_bfloat16* P1I = R1 + 8384;
    __hip_bfloat16* FEAT = R1;
    __hip_bfloat16* H3  = R2;
    __hip_bfloat16* F   = R2;
    __hip_bfloat16* HDB = R2;                 __hip_bfloat16* HDI = R2 + 16576;
    __hip_bfloat16* P2B = (__hip_bfloat16*)R3c; __hip_bfloat16* P2I = P2B + 8576;

    __hip_bfloat16* W2B = (__hip_bfloat16*)(SM + 0);
    __hip_bfloat16* W3B = (__hip_bfloat16*)(SM + 36864);
    __hip_bfloat16* W4B = (__hip_bfloat16*)(SM + 184320);
    __hip_bfloat16* WRB = (__hip_bfloat16*)(SM + 774144);
    __hip_bfloat16* WHB = (__hip_bfloat16*)(SM + 847872);
    __hip_bfloat16* WD1 = (__hip_bfloat16*)(SM + 856064);
    __hip_bfloat16* WD2 = (__hip_bfloat16*)(SM + 1118208);
    float* CO = (float*)(SM + 1183744);
    float* JF = (float*)(SM + 1187968);
    float* RB = (float*)(SM + 1323136);
    float* P  = (float*)(SM + 1325248);
    float* V1 = (float*)(SM + 1587392);
    float* SS = (float*)(SM + 1603840);   // 256 x 4 x 33 f32 = 135168 B

    float* out_hm  = (float*)d_out;        // (16,33,256,256)
    float* out_vis = out_hm + 34603008L;   // (16,33)
    __hip_bfloat16* H2 = (__hip_bfloat16*)d_out;  // scratch: conv2 out, dead before refine

    // ---- weight repacks ----
    repack_conv_w_ilv_k<<<(9*64*32 + 255)/256, 256, 0, stream>>>(c2w, W2B, 9, 64, 32, 64, 32);
    repack_conv_w_ilv_k<<<(9*128*64 + 255)/256, 256, 0, stream>>>(c3w, W3B, 9, 128, 64, 128, 64);
    repack_conv_w_ilv_k<<<(9*256*128 + 255)/256, 256, 0, stream>>>(c4w, W4B, 9, 256, 128, 256, 128);
    repack_conv_w_k<<<(9*64*64 + 255)/256, 256, 0, stream>>>(rw, WRB, 9, 33, 33, 64, 64);
    repack_conv_w_ilv_k<<<(1*64*64 + 255)/256, 256, 0, stream>>>(hw, WHB, 1, 33, 64, 64, 64);
    repack_deconv_w_ilv_k<<<(4*128*256 + 255)/256, 256, 0, stream>>>(d1w, WD1, 128, 256);
    repack_deconv_w_ilv_k<<<(4*64*128 + 255)/256, 256, 0, stream>>>(d2w, WD2, 64, 128);

    // halo zeroing
    zero_halo_k<<<(526336 + 255)/256, 256, 0, stream>>>(H1B, 256, 256, 32, 16);
    zero_halo_k<<<(532480 + 255)/256, 256, 0, stream>>>(P2B, 64, 64, 128, 16);

    // 1) conv1 3->32 @256 -> H1 (padded)
    conv1_k<<<dim3(4, 16, 64), 256, 0, stream>>>(x, c1w, c1b, b1g, b1b, H1I);
    // 2) conv2 32->64 @256 -> H2 (d_out scratch)
    mfma_conv_k<2><<<dim3(512, 1, 16), 256, 0, stream>>>(
        H1I, W2B, c2b, b2g, b2b, H2,
        256, 256, 32, 258, 2130048L, 4194304L, 256, 64, 1, 8);
    // 3) pool -> P1 (padded)
    zero_halo_k<<<(528384 + 255)/256, 256, 0, stream>>>(P1B, 128, 128, 64, 16);
    maxpool_bf_k<<<8192, 256, 0, stream>>>(H2, P1I, 128, 128, 64, 2097152L, 130, 1081600L);
    // 4) conv3 64->128 @128 -> H3
    mfma_conv_k<2><<<dim3(128, 1, 32), 256, 0, stream>>>(
        P1I, W3B, c3b, b3g, b3b, H3,
        128, 128, 64, 130, 1081600L, 2097152L, 128, 128, 2, 4);
    // 5) pool -> P2 (padded)
    maxpool_bf_k<<<4096, 256, 0, stream>>>(H3, P2I, 64, 64, 128, 1048576L, 66, 557568L);
    // 6) conv4 128->256 @64 -> ENC
    mfma_conv_k<2><<<dim3(32, 1, 64), 256, 0, stream>>>(
        P2I, W4B, c4b, b4g, b4b, ENC,
        64, 64, 128, 66, 557568L, 1048576L, 64, 256, 4, 2);
    // 7) dc1 256->128 (64->128 up) -> F
    mfma_deconv_k<<<dim3(32, 1, 32), 256, 0, stream>>>(
        ENC, WD1, d1b, F, 64, 64, 256, 128, 2, 2);
    // 8) dc2 128->64 (128->256 up) -> FEAT
    mfma_deconv_k<<<dim3(128, 1, 16), 256, 0, stream>>>(
        F, WD2, d2b, FEAT, 128, 128, 128, 64, 1, 4);
    // 9) head 1x1 + sigmoid -> HDI (padded bf16 NHWC)
    zero_halo_k<<<(1052672 + 255)/256, 256, 0, stream>>>(HDB, 256, 256, 64, 16);
    mfma_head_k<<<dim3(512, 1, 16), 256, 0, stream>>>(FEAT, WHB, hb, HDI);
    // 10) hierarchical soft-argmax (slabs + combine)
    softargmax_slab_k<<<256, 256, 0, stream>>>(HDI, SS);
    softargmax_comb_k<<<16, 64, 0, stream>>>(SS, CO);
    // 11) bilinear + proj
    joint_bf_k<<<528, 64, 0, stream>>>(FEAT, CO, pw, pb, JF);
    // 12) message + GRU -> refined_bias
    gru_k<<<528, 192, 0, stream>>>(JF, mw, mb, wih, whh, bih, bhh, RB);
    // 13) refine 33->33 @256 + bias + sigmoid -> out_hm (f32 nchw, cooperative stores)
    mfma_refine_k<<<dim3(512, 1, 16), 256, 26880, stream>>>(
        HDI, WRB, rb, RB, out_hm);
    // 14) vis pool -> P (16,4096)
    vispool_bf_k<<<256, 256, 0, stream>>>(ENC, P);
    // 15) fc1 + relu
    visfc1_k<<<16, 256, 0, stream>>>(P, v1w, v1b, V1);
    // 16) fc2 + sigmoid
    visfc2_k<<<16, 64, 0, stream>>>(V1, v2w, v2b, out_vis);
}